// Round 3
// baseline (920.577 us; speedup 1.0000x reference)
//
#include <hip/hip_runtime.h>
#include <hip/hip_bf16.h>
#include <stdint.h>

#define S_LEN 2048
#define EMB   1024
#define NH    16
#define HD    64

typedef unsigned short u16;
typedef __attribute__((ext_vector_type(4))) float f32x4;
typedef __attribute__((ext_vector_type(8))) short bf16x8;

typedef __attribute__((address_space(1))) const unsigned char gas_t;
typedef __attribute__((address_space(3))) unsigned char las_t;

static __device__ __forceinline__ void gld_lds16(const void* g, void* l) {
  __builtin_amdgcn_global_load_lds((gas_t*)g, (las_t*)l, 16, 0, 0);
}

static __device__ __forceinline__ u16 f2bf(float f) {
  unsigned int u = __builtin_bit_cast(unsigned int, f);
  u = u + 0x7fffu + ((u >> 16) & 1u);   // RNE; inputs are finite
  return (u16)(u >> 16);
}

// exp2 in one instruction (v_exp_f32 IS 2^x); args are always <= 0 here.
static __device__ __forceinline__ float fexp2(float x) {
  float r;
  asm("v_exp_f32 %0, %1" : "=v"(r) : "v"(x));
  return r;
}

// pack 2 f32 -> 2 bf16 (RNE) in one instruction; no builtin on gfx950.
static __device__ __forceinline__ unsigned cvt_pk_bf16(float lo, float hi) {
  unsigned r;
  asm("v_cvt_pk_bf16_f32 %0, %1, %2" : "=v"(r) : "v"(lo), "v"(hi));
  return r;
}

// ---------------- x f32 -> bf16 ----------------
__global__ __launch_bounds__(256) void k_cvt(const float* __restrict__ in,
                                             u16* __restrict__ out, int n4) {
  int i = blockIdx.x * blockDim.x + threadIdx.x;
  int stride = gridDim.x * blockDim.x;
  for (; i < n4; i += stride) {
    float4 f = ((const float4*)in)[i];
    ushort4 o;
    o.x = f2bf(f.x); o.y = f2bf(f.y); o.z = f2bf(f.z); o.w = f2bf(f.w);
    ((ushort4*)out)[i] = o;
  }
}

// ---------------- W [K][N] f32 -> WT [N][K] bf16 ----------------
// grid (N/64, K/64), 256 threads
__global__ __launch_bounds__(256) void k_transpose_cvt(const float* __restrict__ W,
                                                       u16* __restrict__ WT,
                                                       int K, int N) {
  __shared__ u16 tile[64][68];
  const int c0 = blockIdx.x * 64, r0 = blockIdx.y * 64;
  const int t = threadIdx.x;
  const int tr = t >> 4, tc4 = (t & 15) * 4;
#pragma unroll
  for (int i = 0; i < 4; i++) {
    const int r = tr + 16 * i;
    float4 f = *(const float4*)&W[(size_t)(r0 + r) * N + c0 + tc4];
    ushort4 o;
    o.x = f2bf(f.x); o.y = f2bf(f.y); o.z = f2bf(f.z); o.w = f2bf(f.w);
    *(ushort4*)&tile[r][tc4] = o;
  }
  __syncthreads();
  const int oc = t >> 2, or0 = (t & 3) * 16;
  u16 vals[16];
#pragma unroll
  for (int j = 0; j < 16; j++) vals[j] = tile[or0 + j][oc];
  u16* dst = &WT[(size_t)(c0 + oc) * K + r0 + or0];
  *(uint4*)dst = *(const uint4*)&vals[0];
  *(uint4*)(dst + 8) = *(const uint4*)&vals[8];
}

// ---------------- GEMM: C[M,N] = A[M,K](bf16) @ BT[N,K]^T + bias ----------------
// 128x128 tile, BK=32, 4 waves (each 64x64 = 4x4 frags of 16x16x32)
// MODE 0: scatter q/k bf16 [B,H,S,D], v bf16 [B,H,D,S] (transposed, vectorized).
// MODE 1: f32 out + bias.
template <int MODE>
__global__ __launch_bounds__(256) void k_gemm(const u16* __restrict__ A,
                                              const u16* __restrict__ BT,
                                              const float* __restrict__ bias,
                                              float* __restrict__ Cout,
                                              u16* __restrict__ q_ws,
                                              u16* __restrict__ k_ws,
                                              u16* __restrict__ v_t,
                                              int N, int K) {
  __shared__ u16 As[128 * 32];
  __shared__ u16 Bs[128 * 32];
  const int tid = threadIdx.x;
  const int w = tid >> 6, lane = tid & 63;
  const int wr = w >> 1, wc = w & 1;
  const int lrow = lane & 15, lk8 = (lane >> 4) * 8;
  const int brow = blockIdx.y * 128, bcol = blockIdx.x * 128;
  const int srow = lane >> 2;          // 0..15 within chunk
  const int scol = (lane & 3) * 8;     // 0,8,16,24

  const f32x4 zero = {0.f, 0.f, 0.f, 0.f};
  f32x4 acc[4][4];
#pragma unroll
  for (int m = 0; m < 4; m++)
#pragma unroll
    for (int n = 0; n < 4; n++) acc[m][n] = zero;

  for (int kt = 0; kt < K; kt += 32) {
#pragma unroll
    for (int i = 0; i < 2; i++) {
      const int c = w * 2 + i;               // chunk 0..7, 1KB each (linear LDS)
      const int row = c * 16 + srow;
      gld_lds16(&A[(size_t)(brow + row) * K + kt + scol], (void*)(As + c * 512));
      gld_lds16(&BT[(size_t)(bcol + row) * K + kt + scol], (void*)(Bs + c * 512));
    }
    __syncthreads();
    bf16x8 af[4], bfr[4];
#pragma unroll
    for (int mt = 0; mt < 4; mt++)
      af[mt] = *(const bf16x8*)&As[(wr * 64 + mt * 16 + lrow) * 32 + lk8];
#pragma unroll
    for (int nt = 0; nt < 4; nt++)
      bfr[nt] = *(const bf16x8*)&Bs[(wc * 64 + nt * 16 + lrow) * 32 + lk8];
    __builtin_amdgcn_s_setprio(1);
#pragma unroll
    for (int mt = 0; mt < 4; mt++)
#pragma unroll
      for (int nt = 0; nt < 4; nt++)
        acc[mt][nt] = __builtin_amdgcn_mfma_f32_16x16x32_bf16(af[mt], bfr[nt],
                                                              acc[mt][nt], 0, 0, 0);
    __builtin_amdgcn_s_setprio(0);
    __syncthreads();
  }

  if constexpr (MODE == 0) {
    const int which = bcol >> 10;   // uniform per block (0=q, 1=k, 2=v)
#pragma unroll
    for (int mt = 0; mt < 4; mt++)
#pragma unroll
      for (int nt = 0; nt < 4; nt++) {
        const int col = bcol + wc * 64 + nt * 16 + lrow;
        const int e = col & 1023;
        const int h = e >> 6, d = e & 63;
        const int row0 = brow + wr * 64 + mt * 16 + (lane >> 4) * 4;
        const int b = row0 >> 11, s0 = row0 & 2047;
        const size_t bh = (size_t)(b * NH + h);
        const float bv = bias[col];
        if (which == 2) {
          ushort4 pk;
          pk.x = f2bf(acc[mt][nt][0] + bv);
          pk.y = f2bf(acc[mt][nt][1] + bv);
          pk.z = f2bf(acc[mt][nt][2] + bv);
          pk.w = f2bf(acc[mt][nt][3] + bv);
          *(ushort4*)&v_t[(bh * HD + d) * S_LEN + s0] = pk;
        } else {
          u16* dst = which ? k_ws : q_ws;
#pragma unroll
          for (int r = 0; r < 4; r++)
            dst[(bh * S_LEN + s0 + r) * HD + d] = f2bf(acc[mt][nt][r] + bv);
        }
      }
  } else {
#pragma unroll
    for (int mt = 0; mt < 4; mt++)
#pragma unroll
      for (int nt = 0; nt < 4; nt++)
#pragma unroll
        for (int r = 0; r < 4; r++) {
          const int row = brow + wr * 64 + mt * 16 + (lane >> 4) * 4 + r;
          const int col = bcol + wc * 64 + nt * 16 + lrow;
          Cout[(size_t)row * N + col] = acc[mt][nt][r] + bias[col];
        }
  }
}

// ---------------- causal flash attention (pair-balanced, double-buffered) ----
// grid (16, B*H), 256 threads. Block pr handles q-tiles {pr, 31-pr} (64 rows
// each); K/V staged once per jb for both, double-buffered (stage jb+1 while
// computing jb; one barrier per tile). Wave w owns rows [w*16,w*16+16).
// V is pre-transposed in global ([b,h,d,s]) so staging mirrors K exactly.
// Softmax runs in log2 domain (scale folds log2(e)); P-store uses cvt_pk.
__global__ __launch_bounds__(256) void k_attn(const u16* __restrict__ q_ws,
                                              const u16* __restrict__ k_ws,
                                              const u16* __restrict__ v_t,
                                              u16* __restrict__ y) {
  __shared__ u16 Kl[2][64 * 64];     // XOR-swizzled rows (16B blocks), [kv][d]
  __shared__ u16 Vl[2][64 * 64];     // XOR-swizzled rows, [d][kv]
  __shared__ u16 Pl[4][16 * 64];     // per-wave P, XOR-swizzled
  const int tid = threadIdx.x;
  const int w = tid >> 6, lane = tid & 63;
  const int lrow = lane & 15, lk8 = (lane >> 4) * 8;
  const int qrow_t = (lane >> 4) * 4;
  const int pr = blockIdx.x;               // 0..15
  const int tileA = pr, tileB = 31 - pr;   // tileA < tileB, work = const 33
  const int bh = blockIdx.y;
  const size_t base = (size_t)bh * S_LEN * HD;
  const float SC = 0.125f * 1.4426950408889634f;  // D^-0.5 * log2(e)

  bf16x8 qfA[2], qfB[2];
#pragma unroll
  for (int ks = 0; ks < 2; ks++) {
    qfA[ks] = *(const bf16x8*)&q_ws[base + (size_t)(tileA * 64 + w * 16 + lrow) * HD + ks * 32 + lk8];
    qfB[ks] = *(const bf16x8*)&q_ws[base + (size_t)(tileB * 64 + w * 16 + lrow) * HD + ks * 32 + lk8];
  }

  const f32x4 zero = {0.f, 0.f, 0.f, 0.f};
  f32x4 oA[4], oB[4];
#pragma unroll
  for (int dt = 0; dt < 4; dt++) { oA[dt] = zero; oB[dt] = zero; }
  float mA[4], lA[4], mB[4], lB[4];
#pragma unroll
  for (int r = 0; r < 4; r++) { mA[r] = -1e30f; lA[r] = 0.f; mB[r] = -1e30f; lB[r] = 0.f; }

  u16* Pw = &Pl[w][0];

  auto stage = [&](int jb, int buf) {
#pragma unroll
    for (int i = 0; i < 2; i++) {
      const int c = w * 2 + i;
      const int row = c * 8 + (lane >> 3);
      const int blk = (lane & 7) ^ (row & 7);
      gld_lds16(&k_ws[base + (size_t)(jb * 64 + row) * HD + blk * 8],
                (void*)(&Kl[buf][0] + c * 512));
      gld_lds16(&v_t[base + (size_t)row * S_LEN + jb * 64 + blk * 8],
                (void*)(&Vl[buf][0] + c * 512));
    }
  };

  auto process = [&](const u16* Kb, const u16* Vb, const bf16x8 (&qf)[2],
                     f32x4 (&o)[4], float (&m_run)[4], float (&l_run)[4],
                     bool maskDiag) {
    // S = Q K^T (per wave: 16 q x 64 kv)
    f32x4 sa[4];
#pragma unroll
    for (int nt = 0; nt < 4; nt++) sa[nt] = zero;
    __builtin_amdgcn_s_setprio(1);
#pragma unroll
    for (int ks = 0; ks < 2; ks++)
#pragma unroll
      for (int nt = 0; nt < 4; nt++) {
        const int kvr = nt * 16 + lrow;
        const int blk = (ks * 4 + (lane >> 4)) ^ (kvr & 7);
        bf16x8 kf = *(const bf16x8*)((const char*)Kb + kvr * 128 + blk * 16);
        sa[nt] = __builtin_amdgcn_mfma_f32_16x16x32_bf16(qf[ks], kf, sa[nt], 0, 0, 0);
      }
    __builtin_amdgcn_s_setprio(0);

    float sv[4][4];
#pragma unroll
    for (int nt = 0; nt < 4; nt++)
#pragma unroll
      for (int r = 0; r < 4; r++) {
        float x = sa[nt][r] * SC;            // log2 domain
        if (maskDiag && (nt * 16 + lrow) > (w * 16 + qrow_t + r)) x = -3.0e38f;
        sv[nt][r] = x;
      }

    // online softmax in log2 domain (rows live in 16-lane groups)
#pragma unroll
    for (int r = 0; r < 4; r++) {
      float mx = fmaxf(fmaxf(sv[0][r], sv[1][r]), fmaxf(sv[2][r], sv[3][r]));
      mx = fmaxf(mx, __shfl_xor(mx, 1));
      mx = fmaxf(mx, __shfl_xor(mx, 2));
      mx = fmaxf(mx, __shfl_xor(mx, 4));
      mx = fmaxf(mx, __shfl_xor(mx, 8));
      const float mn = fmaxf(m_run[r], mx);
      const float alpha = fexp2(m_run[r] - mn);
      float sum = 0.f;
#pragma unroll
      for (int nt = 0; nt < 4; nt++) {
        const float p = fexp2(sv[nt][r] - mn);
        sv[nt][r] = p;
        sum += p;
      }
      sum += __shfl_xor(sum, 1);
      sum += __shfl_xor(sum, 2);
      sum += __shfl_xor(sum, 4);
      sum += __shfl_xor(sum, 8);
      l_run[r] = l_run[r] * alpha + sum;
      m_run[r] = mn;
#pragma unroll
      for (int dt = 0; dt < 4; dt++) o[dt][r] *= alpha;
    }

    // P -> per-wave LDS (bf16 via cvt_pk, swizzled); rows qrow_t+0..3
#pragma unroll
    for (int nt = 0; nt < 4; nt++) {
      const unsigned pk0 = cvt_pk_bf16(sv[nt][0], sv[nt][1]);
      const unsigned pk1 = cvt_pk_bf16(sv[nt][2], sv[nt][3]);
      const int col2 = (nt * 16 + lrow) * 2;
      char* pb = (char*)Pw;
      *(u16*)(pb + (qrow_t + 0) * 128 + (col2 ^ (((qrow_t + 0) & 7) << 4))) = (u16)pk0;
      *(u16*)(pb + (qrow_t + 1) * 128 + (col2 ^ (((qrow_t + 1) & 7) << 4))) = (u16)(pk0 >> 16);
      *(u16*)(pb + (qrow_t + 2) * 128 + (col2 ^ (((qrow_t + 2) & 7) << 4))) = (u16)pk1;
      *(u16*)(pb + (qrow_t + 3) * 128 + (col2 ^ (((qrow_t + 3) & 7) << 4))) = (u16)(pk1 >> 16);
    }

    // O += P @ V
    __builtin_amdgcn_s_setprio(1);
#pragma unroll
    for (int ks = 0; ks < 2; ks++) {
      const int blk = (ks * 4 + (lane >> 4)) ^ (lrow & 7);
      bf16x8 pf = *(const bf16x8*)((const char*)Pw + lrow * 128 + blk * 16);
#pragma unroll
      for (int dt = 0; dt < 4; dt++) {
        const int vr = dt * 16 + lrow;
        const int vblk = (ks * 4 + (lane >> 4)) ^ (vr & 7);
        bf16x8 vf = *(const bf16x8*)((const char*)Vb + vr * 128 + vblk * 16);
        o[dt] = __builtin_amdgcn_mfma_f32_16x16x32_bf16(pf, vf, o[dt], 0, 0, 0);
      }
    }
    __builtin_amdgcn_s_setprio(0);
  };

  auto doTile = [&](int jb, int buf) {
    const u16* Kb = &Kl[buf][0];
    const u16* Vb = &Vl[buf][0];
    process(Kb, Vb, qfB, oB, mB, lB, jb == tileB);
    if (jb <= tileA) process(Kb, Vb, qfA, oA, mA, lA, jb == tileA);
  };

  const int NT = tileB + 1;          // 17..32 tiles
  stage(0, 0);
  __syncthreads();
  int jb = 0;
  while (true) {
    if (jb + 1 < NT) stage(jb + 1, 1);
    doTile(jb, 0);
    __syncthreads();
    if (++jb >= NT) break;
    if (jb + 1 < NT) stage(jb + 1, 0);
    doTile(jb, 1);
    __syncthreads();
    if (++jb >= NT) break;
  }

  const int b = bh >> 4, h = bh & 15;
#pragma unroll
  for (int r = 0; r < 4; r++) {
    const float invA = 1.0f / lA[r];
    const float invB = 1.0f / lB[r];
    const int qgA = tileA * 64 + w * 16 + qrow_t + r;
    const int qgB = tileB * 64 + w * 16 + qrow_t + r;
#pragma unroll
    for (int dt = 0; dt < 4; dt++) {
      y[((size_t)(b * S_LEN + qgA)) * EMB + h * HD + dt * 16 + lrow] = f2bf(oA[dt][r] * invA);
      y[((size_t)(b * S_LEN + qgB)) * EMB + h * HD + dt * 16 + lrow] = f2bf(oB[dt][r] * invB);
    }
  }
}

extern "C" void kernel_launch(void* const* d_in, const int* in_sizes, int n_in,
                              void* d_out, int out_size, void* d_ws, size_t ws_size,
                              hipStream_t stream) {
  const float* x      = (const float*)d_in[0];
  const float* w_qkv  = (const float*)d_in[1];
  const float* b_qkv  = (const float*)d_in[2];
  const float* w_proj = (const float*)d_in[3];
  const float* b_proj = (const float*)d_in[4];
  float* out = (float*)d_out;

  char* ws = (char*)d_ws;
  u16* wqkvT  = (u16*)(ws);                  // 3072x1024 bf16 (6 MB)
  u16* wprojT = (u16*)(ws + 6291456);        // 1024x1024 bf16 (2 MB)
  u16* xb     = (u16*)(ws + 8388608);        // 8192x1024 bf16 (16 MB), reused as y_att
  u16* q_ws   = (u16*)(ws + 25165824);       // [B,H,S,D] bf16 (16 MB)
  u16* k_ws   = (u16*)(ws + 41943040);       // [B,H,S,D]
  u16* v_t    = (u16*)(ws + 58720256);       // [B,H,D,S] (transposed!)  end: 72 MB
  u16* y_att  = xb;                          // x dead after GEMM1

  k_cvt<<<dim3(1024), dim3(256), 0, stream>>>(x, xb, (8192 * 1024) / 4);
  k_transpose_cvt<<<dim3(48, 16), dim3(256), 0, stream>>>(w_qkv, wqkvT, 1024, 3072);
  k_transpose_cvt<<<dim3(16, 16), dim3(256), 0, stream>>>(w_proj, wprojT, 1024, 1024);
  k_gemm<0><<<dim3(24, 64), dim3(256), 0, stream>>>(xb, wqkvT, b_qkv, nullptr,
                                                    q_ws, k_ws, v_t, 3072, 1024);
  k_attn<<<dim3(16, 64), dim3(256), 0, stream>>>(q_ws, k_ws, v_t, y_att);
  k_gemm<1><<<dim3(8, 64), dim3(256), 0, stream>>>(y_att, wprojT, b_proj, out,
                                                   nullptr, nullptr, nullptr, 1024, 1024);
}

// Round 4
// 247.192 us; speedup vs baseline: 3.7241x; 3.7241x over previous
//
#include <hip/hip_runtime.h>
#include <hip/hip_bf16.h>
#include <stdint.h>

#define S_LEN 2048
#define EMB   1024
#define NH    16
#define HD    64

typedef unsigned short u16;
typedef __attribute__((ext_vector_type(4))) float f32x4;
typedef __attribute__((ext_vector_type(8))) short bf16x8;

typedef __attribute__((address_space(1))) const unsigned char gas_t;
typedef __attribute__((address_space(3))) unsigned char las_t;

static __device__ __forceinline__ void gld_lds16(const void* g, void* l) {
  __builtin_amdgcn_global_load_lds((gas_t*)g, (las_t*)l, 16, 0, 0);
}

static __device__ __forceinline__ u16 f2bf(float f) {
  unsigned int u = __builtin_bit_cast(unsigned int, f);
  u = u + 0x7fffu + ((u >> 16) & 1u);   // RNE; inputs are finite
  return (u16)(u >> 16);
}

// exp2 in one instruction (v_exp_f32 IS 2^x).
static __device__ __forceinline__ float fexp2(float x) {
  float r;
  asm("v_exp_f32 %0, %1" : "=v"(r) : "v"(x));
  return r;
}

// pack 2 f32 -> 2 bf16 (RNE) in one instruction; no builtin on gfx950.
static __device__ __forceinline__ unsigned cvt_pk_bf16(float lo, float hi) {
  unsigned r;
  asm("v_cvt_pk_bf16_f32 %0, %1, %2" : "=v"(r) : "v"(lo), "v"(hi));
  return r;
}

// ---------------- x f32 -> bf16 ----------------
__global__ __launch_bounds__(256) void k_cvt(const float* __restrict__ in,
                                             u16* __restrict__ out, int n4) {
  int i = blockIdx.x * blockDim.x + threadIdx.x;
  int stride = gridDim.x * blockDim.x;
  for (; i < n4; i += stride) {
    float4 f = ((const float4*)in)[i];
    ushort4 o;
    o.x = f2bf(f.x); o.y = f2bf(f.y); o.z = f2bf(f.z); o.w = f2bf(f.w);
    ((ushort4*)out)[i] = o;
  }
}

// ---------------- W [K][N] f32 -> WT [N][K] bf16 ----------------
// grid (N/64, K/64), 256 threads
__global__ __launch_bounds__(256) void k_transpose_cvt(const float* __restrict__ W,
                                                       u16* __restrict__ WT,
                                                       int K, int N) {
  __shared__ u16 tile[64][68];
  const int c0 = blockIdx.x * 64, r0 = blockIdx.y * 64;
  const int t = threadIdx.x;
  const int tr = t >> 4, tc4 = (t & 15) * 4;
#pragma unroll
  for (int i = 0; i < 4; i++) {
    const int r = tr + 16 * i;
    float4 f = *(const float4*)&W[(size_t)(r0 + r) * N + c0 + tc4];
    ushort4 o;
    o.x = f2bf(f.x); o.y = f2bf(f.y); o.z = f2bf(f.z); o.w = f2bf(f.w);
    *(ushort4*)&tile[r][tc4] = o;
  }
  __syncthreads();
  const int oc = t >> 2, or0 = (t & 3) * 16;
  u16 vals[16];
#pragma unroll
  for (int j = 0; j < 16; j++) vals[j] = tile[or0 + j][oc];
  u16* dst = &WT[(size_t)(c0 + oc) * K + r0 + or0];
  *(uint4*)dst = *(const uint4*)&vals[0];
  *(uint4*)(dst + 8) = *(const uint4*)&vals[8];
}

// ---------------- GEMM: C[M,N] = A[M,K](bf16) @ BT[N,K]^T + bias ----------------
// 128x128 tile, BK=32, 4 waves (each 64x64 = 4x4 frags of 16x16x32)
// MODE 0: scatter q/k bf16 [B,H,S,D], v bf16 [B,H,D,S] (transposed, vectorized).
// MODE 1: f32 out + bias.
template <int MODE>
__global__ __launch_bounds__(256) void k_gemm(const u16* __restrict__ A,
                                              const u16* __restrict__ BT,
                                              const float* __restrict__ bias,
                                              float* __restrict__ Cout,
                                              u16* __restrict__ q_ws,
                                              u16* __restrict__ k_ws,
                                              u16* __restrict__ v_t,
                                              int N, int K) {
  __shared__ u16 As[128 * 32];
  __shared__ u16 Bs[128 * 32];
  const int tid = threadIdx.x;
  const int w = tid >> 6, lane = tid & 63;
  const int wr = w >> 1, wc = w & 1;
  const int lrow = lane & 15, lk8 = (lane >> 4) * 8;
  const int brow = blockIdx.y * 128, bcol = blockIdx.x * 128;
  const int srow = lane >> 2;          // 0..15 within chunk
  const int scol = (lane & 3) * 8;     // 0,8,16,24

  const f32x4 zero = {0.f, 0.f, 0.f, 0.f};
  f32x4 acc[4][4];
#pragma unroll
  for (int m = 0; m < 4; m++)
#pragma unroll
    for (int n = 0; n < 4; n++) acc[m][n] = zero;

  for (int kt = 0; kt < K; kt += 32) {
#pragma unroll
    for (int i = 0; i < 2; i++) {
      const int c = w * 2 + i;               // chunk 0..7, 1KB each (linear LDS)
      const int row = c * 16 + srow;
      gld_lds16(&A[(size_t)(brow + row) * K + kt + scol], (void*)(As + c * 512));
      gld_lds16(&BT[(size_t)(bcol + row) * K + kt + scol], (void*)(Bs + c * 512));
    }
    __syncthreads();
    bf16x8 af[4], bfr[4];
#pragma unroll
    for (int mt = 0; mt < 4; mt++)
      af[mt] = *(const bf16x8*)&As[(wr * 64 + mt * 16 + lrow) * 32 + lk8];
#pragma unroll
    for (int nt = 0; nt < 4; nt++)
      bfr[nt] = *(const bf16x8*)&Bs[(wc * 64 + nt * 16 + lrow) * 32 + lk8];
    __builtin_amdgcn_s_setprio(1);
#pragma unroll
    for (int mt = 0; mt < 4; mt++)
#pragma unroll
      for (int nt = 0; nt < 4; nt++)
        acc[mt][nt] = __builtin_amdgcn_mfma_f32_16x16x32_bf16(af[mt], bfr[nt],
                                                              acc[mt][nt], 0, 0, 0);
    __builtin_amdgcn_s_setprio(0);
    __syncthreads();
  }

  if constexpr (MODE == 0) {
    const int which = bcol >> 10;   // uniform per block (0=q, 1=k, 2=v)
#pragma unroll
    for (int mt = 0; mt < 4; mt++)
#pragma unroll
      for (int nt = 0; nt < 4; nt++) {
        const int col = bcol + wc * 64 + nt * 16 + lrow;
        const int e = col & 1023;
        const int h = e >> 6, d = e & 63;
        const int row0 = brow + wr * 64 + mt * 16 + (lane >> 4) * 4;
        const int b = row0 >> 11, s0 = row0 & 2047;
        const size_t bh = (size_t)(b * NH + h);
        const float bv = bias[col];
        if (which == 2) {
          ushort4 pk;
          pk.x = f2bf(acc[mt][nt][0] + bv);
          pk.y = f2bf(acc[mt][nt][1] + bv);
          pk.z = f2bf(acc[mt][nt][2] + bv);
          pk.w = f2bf(acc[mt][nt][3] + bv);
          *(ushort4*)&v_t[(bh * HD + d) * S_LEN + s0] = pk;
        } else {
          u16* dst = which ? k_ws : q_ws;
#pragma unroll
          for (int r = 0; r < 4; r++)
            dst[(bh * S_LEN + s0 + r) * HD + d] = f2bf(acc[mt][nt][r] + bv);
        }
      }
  } else {
#pragma unroll
    for (int mt = 0; mt < 4; mt++)
#pragma unroll
      for (int nt = 0; nt < 4; nt++)
#pragma unroll
        for (int r = 0; r < 4; r++) {
          const int row = brow + wr * 64 + mt * 16 + (lane >> 4) * 4 + r;
          const int col = bcol + wc * 64 + nt * 16 + lrow;
          Cout[(size_t)row * N + col] = acc[mt][nt][r] + bias[col];
        }
  }
}

// ---------------- causal flash attention (pair-balanced, double-buffered) ----
// grid (16, B*H), 256 threads. Block pr handles q-tiles {pr, 31-pr}; K/V staged
// once per jb for both tiles, double-buffered with ONE barrier per tile
// (prefetch jb+1 into buf cur^1 before computing jb; the compiler's
// vmcnt(0)-before-s_barrier makes the prefetch ready at the next iteration).
// Shared arrays are indexed DIRECTLY inside process (addrspace(3) provable —
// round-3 regression came from generic-pointer params + 4x body duplication
// causing a 56-VGPR spill cliff). __launch_bounds__(256,2) caps the allocator
// at 256 VGPRs so it never targets spill-level occupancy.
__global__ __launch_bounds__(256, 2) void k_attn(const u16* __restrict__ q_ws,
                                                 const u16* __restrict__ k_ws,
                                                 const u16* __restrict__ v_t,
                                                 u16* __restrict__ y) {
  __shared__ u16 Kl[2][64 * 64];     // XOR-swizzled rows (16B blocks), [kv][d]
  __shared__ u16 Vl[2][64 * 64];     // XOR-swizzled rows, [d][kv]
  __shared__ u16 Pl[4][16 * 64];     // per-wave P, XOR-swizzled
  const int tid = threadIdx.x;
  const int w = tid >> 6, lane = tid & 63;
  const int lrow = lane & 15, lk8 = (lane >> 4) * 8;
  const int qrow_t = (lane >> 4) * 4;
  const int pr = blockIdx.x;               // 0..15
  const int tileA = pr, tileB = 31 - pr;   // tileA < tileB, work = const 33
  const int bh = blockIdx.y;
  const size_t base = (size_t)bh * S_LEN * HD;
  const float SC = 0.125f * 1.4426950408889634f;  // D^-0.5 * log2(e)

  bf16x8 qfA[2], qfB[2];
#pragma unroll
  for (int ks = 0; ks < 2; ks++) {
    qfA[ks] = *(const bf16x8*)&q_ws[base + (size_t)(tileA * 64 + w * 16 + lrow) * HD + ks * 32 + lk8];
    qfB[ks] = *(const bf16x8*)&q_ws[base + (size_t)(tileB * 64 + w * 16 + lrow) * HD + ks * 32 + lk8];
  }

  const f32x4 zero = {0.f, 0.f, 0.f, 0.f};
  f32x4 oA[4], oB[4];
#pragma unroll
  for (int dt = 0; dt < 4; dt++) { oA[dt] = zero; oB[dt] = zero; }
  float mA[4], lA[4], mB[4], lB[4];
#pragma unroll
  for (int r = 0; r < 4; r++) { mA[r] = -1e30f; lA[r] = 0.f; mB[r] = -1e30f; lB[r] = 0.f; }

  u16* Pw = &Pl[w][0];

  auto stage = [&](int jb, int buf) {
#pragma unroll
    for (int i = 0; i < 2; i++) {
      const int c = w * 2 + i;
      const int row = c * 8 + (lane >> 3);
      const int blk = (lane & 7) ^ (row & 7);
      gld_lds16(&k_ws[base + (size_t)(jb * 64 + row) * HD + blk * 8],
                (void*)(&Kl[buf][c * 512]));
      gld_lds16(&v_t[base + (size_t)row * S_LEN + jb * 64 + blk * 8],
                (void*)(&Vl[buf][c * 512]));
    }
  };

  // cur: which K/V buffer to read (runtime 0/1 — plain LDS address math).
  auto process = [&](int cur, const bf16x8 (&qf)[2], f32x4 (&o)[4],
                     float (&m_run)[4], float (&l_run)[4], bool maskDiag) {
    // S = Q K^T (per wave: 16 q x 64 kv)
    f32x4 sa[4];
#pragma unroll
    for (int nt = 0; nt < 4; nt++) sa[nt] = zero;
    __builtin_amdgcn_s_setprio(1);
#pragma unroll
    for (int ks = 0; ks < 2; ks++)
#pragma unroll
      for (int nt = 0; nt < 4; nt++) {
        const int kvr = nt * 16 + lrow;
        const int blk = (ks * 4 + (lane >> 4)) ^ (kvr & 7);
        bf16x8 kf = *(const bf16x8*)&Kl[cur][kvr * 64 + blk * 8];
        sa[nt] = __builtin_amdgcn_mfma_f32_16x16x32_bf16(qf[ks], kf, sa[nt], 0, 0, 0);
      }
    __builtin_amdgcn_s_setprio(0);

    float sv[4][4];
#pragma unroll
    for (int nt = 0; nt < 4; nt++)
#pragma unroll
      for (int r = 0; r < 4; r++) {
        float x = sa[nt][r] * SC;            // log2 domain
        if (maskDiag && (nt * 16 + lrow) > (w * 16 + qrow_t + r)) x = -3.0e38f;
        sv[nt][r] = x;
      }

    // online softmax in log2 domain (rows live in 16-lane groups)
#pragma unroll
    for (int r = 0; r < 4; r++) {
      float mx = fmaxf(fmaxf(sv[0][r], sv[1][r]), fmaxf(sv[2][r], sv[3][r]));
      mx = fmaxf(mx, __shfl_xor(mx, 1));
      mx = fmaxf(mx, __shfl_xor(mx, 2));
      mx = fmaxf(mx, __shfl_xor(mx, 4));
      mx = fmaxf(mx, __shfl_xor(mx, 8));
      const float mn = fmaxf(m_run[r], mx);
      const float alpha = fexp2(m_run[r] - mn);
      float sum = 0.f;
#pragma unroll
      for (int nt = 0; nt < 4; nt++) {
        const float p = fexp2(sv[nt][r] - mn);
        sv[nt][r] = p;
        sum += p;
      }
      sum += __shfl_xor(sum, 1);
      sum += __shfl_xor(sum, 2);
      sum += __shfl_xor(sum, 4);
      sum += __shfl_xor(sum, 8);
      l_run[r] = l_run[r] * alpha + sum;
      m_run[r] = mn;
#pragma unroll
      for (int dt = 0; dt < 4; dt++) o[dt][r] *= alpha;
    }

    // P -> per-wave LDS (bf16 via cvt_pk, swizzled); rows qrow_t+0..3
#pragma unroll
    for (int nt = 0; nt < 4; nt++) {
      const unsigned pk0 = cvt_pk_bf16(sv[nt][0], sv[nt][1]);
      const unsigned pk1 = cvt_pk_bf16(sv[nt][2], sv[nt][3]);
      const int col2 = (nt * 16 + lrow) * 2;
      char* pb = (char*)Pw;
      *(u16*)(pb + (qrow_t + 0) * 128 + (col2 ^ (((qrow_t + 0) & 7) << 4))) = (u16)pk0;
      *(u16*)(pb + (qrow_t + 1) * 128 + (col2 ^ (((qrow_t + 1) & 7) << 4))) = (u16)(pk0 >> 16);
      *(u16*)(pb + (qrow_t + 2) * 128 + (col2 ^ (((qrow_t + 2) & 7) << 4))) = (u16)pk1;
      *(u16*)(pb + (qrow_t + 3) * 128 + (col2 ^ (((qrow_t + 3) & 7) << 4))) = (u16)(pk1 >> 16);
    }

    // O += P @ V
    __builtin_amdgcn_s_setprio(1);
#pragma unroll
    for (int ks = 0; ks < 2; ks++) {
      const int blk = (ks * 4 + (lane >> 4)) ^ (lrow & 7);
      bf16x8 pf = *(const bf16x8*)((const char*)Pw + lrow * 128 + blk * 16);
#pragma unroll
      for (int dt = 0; dt < 4; dt++) {
        const int vr = dt * 16 + lrow;
        const int vblk = (ks * 4 + (lane >> 4)) ^ (vr & 7);
        bf16x8 vf = *(const bf16x8*)&Vl[cur][vr * 64 + vblk * 8];
        o[dt] = __builtin_amdgcn_mfma_f32_16x16x32_bf16(pf, vf, o[dt], 0, 0, 0);
      }
    }
    __builtin_amdgcn_s_setprio(0);
  };

  stage(0, 0);
  __syncthreads();
  for (int jb = 0; jb <= tileB; jb++) {
    const int cur = jb & 1;
    if (jb < tileB) stage(jb + 1, cur ^ 1);
    process(cur, qfB, oB, mB, lB, jb == tileB);
    if (jb <= tileA) process(cur, qfA, oA, mA, lA, jb == tileA);
    __syncthreads();
  }

  const int b = bh >> 4, h = bh & 15;
#pragma unroll
  for (int r = 0; r < 4; r++) {
    const float invA = 1.0f / lA[r];
    const float invB = 1.0f / lB[r];
    const int qgA = tileA * 64 + w * 16 + qrow_t + r;
    const int qgB = tileB * 64 + w * 16 + qrow_t + r;
#pragma unroll
    for (int dt = 0; dt < 4; dt++) {
      y[((size_t)(b * S_LEN + qgA)) * EMB + h * HD + dt * 16 + lrow] = f2bf(oA[dt][r] * invA);
      y[((size_t)(b * S_LEN + qgB)) * EMB + h * HD + dt * 16 + lrow] = f2bf(oB[dt][r] * invB);
    }
  }
}

extern "C" void kernel_launch(void* const* d_in, const int* in_sizes, int n_in,
                              void* d_out, int out_size, void* d_ws, size_t ws_size,
                              hipStream_t stream) {
  const float* x      = (const float*)d_in[0];
  const float* w_qkv  = (const float*)d_in[1];
  const float* b_qkv  = (const float*)d_in[2];
  const float* w_proj = (const float*)d_in[3];
  const float* b_proj = (const float*)d_in[4];
  float* out = (float*)d_out;

  char* ws = (char*)d_ws;
  u16* wqkvT  = (u16*)(ws);                  // 3072x1024 bf16 (6 MB)
  u16* wprojT = (u16*)(ws + 6291456);        // 1024x1024 bf16 (2 MB)
  u16* xb     = (u16*)(ws + 8388608);        // 8192x1024 bf16 (16 MB), reused as y_att
  u16* q_ws   = (u16*)(ws + 25165824);       // [B,H,S,D] bf16 (16 MB)
  u16* k_ws   = (u16*)(ws + 41943040);       // [B,H,S,D]
  u16* v_t    = (u16*)(ws + 58720256);       // [B,H,D,S] (transposed!)  end: 72 MB
  u16* y_att  = xb;                          // x dead after GEMM1

  k_cvt<<<dim3(1024), dim3(256), 0, stream>>>(x, xb, (8192 * 1024) / 4);
  k_transpose_cvt<<<dim3(48, 16), dim3(256), 0, stream>>>(w_qkv, wqkvT, 1024, 3072);
  k_transpose_cvt<<<dim3(16, 16), dim3(256), 0, stream>>>(w_proj, wprojT, 1024, 1024);
  k_gemm<0><<<dim3(24, 64), dim3(256), 0, stream>>>(xb, wqkvT, b_qkv, nullptr,
                                                    q_ws, k_ws, v_t, 3072, 1024);
  k_attn<<<dim3(16, 64), dim3(256), 0, stream>>>(q_ws, k_ws, v_t, y_att);
  k_gemm<1><<<dim3(8, 64), dim3(256), 0, stream>>>(y_att, wprojT, b_proj, out,
                                                   nullptr, nullptr, nullptr, 1024, 1024);
}

// Round 5
// 216.132 us; speedup vs baseline: 4.2593x; 1.1437x over previous
//
#include <hip/hip_runtime.h>
#include <hip/hip_bf16.h>
#include <stdint.h>

#define S_LEN 2048
#define EMB   1024
#define NH    16
#define HD    64

typedef unsigned short u16;
typedef __attribute__((ext_vector_type(4))) float f32x4;
typedef __attribute__((ext_vector_type(8))) short bf16x8;

typedef __attribute__((address_space(1))) const unsigned char gas_t;
typedef __attribute__((address_space(3))) unsigned char las_t;

static __device__ __forceinline__ void gld_lds16(const void* g, void* l) {
  __builtin_amdgcn_global_load_lds((gas_t*)g, (las_t*)l, 16, 0, 0);
}

static __device__ __forceinline__ u16 f2bf(float f) {
  unsigned int u = __builtin_bit_cast(unsigned int, f);
  u = u + 0x7fffu + ((u >> 16) & 1u);   // RNE; inputs are finite
  return (u16)(u >> 16);
}

// exp2 in one instruction (v_exp_f32 IS 2^x).
static __device__ __forceinline__ float fexp2(float x) {
  float r;
  asm("v_exp_f32 %0, %1" : "=v"(r) : "v"(x));
  return r;
}

// pack 2 f32 -> 2 bf16 (RNE) in one instruction; no builtin on gfx950.
static __device__ __forceinline__ unsigned cvt_pk_bf16(float lo, float hi) {
  unsigned r;
  asm("v_cvt_pk_bf16_f32 %0, %1, %2" : "=v"(r) : "v"(lo), "v"(hi));
  return r;
}

// 16-lane reduce via DPP (VALU pipe) instead of __shfl_xor (ds_swizzle = LDS
// pipe, which is the saturated resource in k_attn). Sequence: xor1 (quad_perm
// 0xB1), xor2 (quad_perm 0x4E), row_mirror 0x140 (^15; quad-uniform by then so
// merges quads {q,3-q}), row_half_mirror 0x141 (^7; merges quads {q,q^1}).
template <int CTRL>
static __device__ __forceinline__ float dppmax(float x) {
  int s = __builtin_amdgcn_update_dpp(0, __builtin_bit_cast(int, x), CTRL, 0xf, 0xf, true);
  return fmaxf(x, __builtin_bit_cast(float, s));
}
template <int CTRL>
static __device__ __forceinline__ float dppadd(float x) {
  int s = __builtin_amdgcn_update_dpp(0, __builtin_bit_cast(int, x), CTRL, 0xf, 0xf, true);
  return x + __builtin_bit_cast(float, s);
}
static __device__ __forceinline__ float red16_max(float x) {
  x = dppmax<0xB1>(x); x = dppmax<0x4E>(x);
  x = dppmax<0x140>(x); x = dppmax<0x141>(x);
  return x;
}
static __device__ __forceinline__ float red16_sum(float x) {
  x = dppadd<0xB1>(x); x = dppadd<0x4E>(x);
  x = dppadd<0x140>(x); x = dppadd<0x141>(x);
  return x;
}

// ---------------- x f32 -> bf16 ----------------
__global__ __launch_bounds__(256) void k_cvt(const float* __restrict__ in,
                                             u16* __restrict__ out, int n4) {
  int i = blockIdx.x * blockDim.x + threadIdx.x;
  int stride = gridDim.x * blockDim.x;
  for (; i < n4; i += stride) {
    float4 f = ((const float4*)in)[i];
    ushort4 o;
    o.x = f2bf(f.x); o.y = f2bf(f.y); o.z = f2bf(f.z); o.w = f2bf(f.w);
    ((ushort4*)out)[i] = o;
  }
}

// ---------------- W [K][N] f32 -> WT [N][K] bf16 ----------------
// grid (N/64, K/64), 256 threads
__global__ __launch_bounds__(256) void k_transpose_cvt(const float* __restrict__ W,
                                                       u16* __restrict__ WT,
                                                       int K, int N) {
  __shared__ u16 tile[64][68];
  const int c0 = blockIdx.x * 64, r0 = blockIdx.y * 64;
  const int t = threadIdx.x;
  const int tr = t >> 4, tc4 = (t & 15) * 4;
#pragma unroll
  for (int i = 0; i < 4; i++) {
    const int r = tr + 16 * i;
    float4 f = *(const float4*)&W[(size_t)(r0 + r) * N + c0 + tc4];
    ushort4 o;
    o.x = f2bf(f.x); o.y = f2bf(f.y); o.z = f2bf(f.z); o.w = f2bf(f.w);
    *(ushort4*)&tile[r][tc4] = o;
  }
  __syncthreads();
  const int oc = t >> 2, or0 = (t & 3) * 16;
  u16 vals[16];
#pragma unroll
  for (int j = 0; j < 16; j++) vals[j] = tile[or0 + j][oc];
  u16* dst = &WT[(size_t)(c0 + oc) * K + r0 + or0];
  *(uint4*)dst = *(const uint4*)&vals[0];
  *(uint4*)(dst + 8) = *(const uint4*)&vals[8];
}

// ---------------- GEMM: C[M,N] = A[M,K](bf16) @ BT[N,K]^T + bias ----------------
// 128x128 tile, BK=32, 4 waves (each 64x64 = 4x4 frags of 16x16x32),
// double-buffered LDS (one barrier per k-step; prefetch k-step+1 while
// computing k-step — pattern validated in k_attn R4).
// MODE 0: scatter q/k bf16 [B,H,S,D], v bf16 [B,H,D,S] (transposed, vectorized).
// MODE 1: f32 out + bias.
template <int MODE>
__global__ __launch_bounds__(256) void k_gemm(const u16* __restrict__ A,
                                              const u16* __restrict__ BT,
                                              const float* __restrict__ bias,
                                              float* __restrict__ Cout,
                                              u16* __restrict__ q_ws,
                                              u16* __restrict__ k_ws,
                                              u16* __restrict__ v_t,
                                              int N, int K) {
  __shared__ u16 As[2][128 * 32];
  __shared__ u16 Bs[2][128 * 32];
  const int tid = threadIdx.x;
  const int w = tid >> 6, lane = tid & 63;
  const int wr = w >> 1, wc = w & 1;
  const int lrow = lane & 15, lk8 = (lane >> 4) * 8;
  const int brow = blockIdx.y * 128, bcol = blockIdx.x * 128;
  const int srow = lane >> 2;          // 0..15 within chunk
  const int scol = (lane & 3) * 8;     // 0,8,16,24

  const f32x4 zero = {0.f, 0.f, 0.f, 0.f};
  f32x4 acc[4][4];
#pragma unroll
  for (int m = 0; m < 4; m++)
#pragma unroll
    for (int n = 0; n < 4; n++) acc[m][n] = zero;

  auto stage = [&](int kt, int buf) {
#pragma unroll
    for (int i = 0; i < 2; i++) {
      const int c = w * 2 + i;               // chunk 0..7, 1KB each (linear LDS)
      const int row = c * 16 + srow;
      gld_lds16(&A[(size_t)(brow + row) * K + kt + scol], (void*)(&As[buf][c * 512]));
      gld_lds16(&BT[(size_t)(bcol + row) * K + kt + scol], (void*)(&Bs[buf][c * 512]));
    }
  };

  const int NK = K >> 5;
  stage(0, 0);
  __syncthreads();
  for (int it = 0; it < NK; ++it) {
    const int cur = it & 1;
    if (it + 1 < NK) stage((it + 1) << 5, cur ^ 1);
    bf16x8 af[4], bfr[4];
#pragma unroll
    for (int mt = 0; mt < 4; mt++)
      af[mt] = *(const bf16x8*)&As[cur][(wr * 64 + mt * 16 + lrow) * 32 + lk8];
#pragma unroll
    for (int nt = 0; nt < 4; nt++)
      bfr[nt] = *(const bf16x8*)&Bs[cur][(wc * 64 + nt * 16 + lrow) * 32 + lk8];
    __builtin_amdgcn_s_setprio(1);
#pragma unroll
    for (int mt = 0; mt < 4; mt++)
#pragma unroll
      for (int nt = 0; nt < 4; nt++)
        acc[mt][nt] = __builtin_amdgcn_mfma_f32_16x16x32_bf16(af[mt], bfr[nt],
                                                              acc[mt][nt], 0, 0, 0);
    __builtin_amdgcn_s_setprio(0);
    __syncthreads();
  }

  if constexpr (MODE == 0) {
    const int which = bcol >> 10;   // uniform per block (0=q, 1=k, 2=v)
#pragma unroll
    for (int mt = 0; mt < 4; mt++)
#pragma unroll
      for (int nt = 0; nt < 4; nt++) {
        const int col = bcol + wc * 64 + nt * 16 + lrow;
        const int e = col & 1023;
        const int h = e >> 6, d = e & 63;
        const int row0 = brow + wr * 64 + mt * 16 + (lane >> 4) * 4;
        const int b = row0 >> 11, s0 = row0 & 2047;
        const size_t bh = (size_t)(b * NH + h);
        const float bv = bias[col];
        if (which == 2) {
          ushort4 pk;
          pk.x = f2bf(acc[mt][nt][0] + bv);
          pk.y = f2bf(acc[mt][nt][1] + bv);
          pk.z = f2bf(acc[mt][nt][2] + bv);
          pk.w = f2bf(acc[mt][nt][3] + bv);
          *(ushort4*)&v_t[(bh * HD + d) * S_LEN + s0] = pk;
        } else {
          u16* dst = which ? k_ws : q_ws;
#pragma unroll
          for (int r = 0; r < 4; r++)
            dst[(bh * S_LEN + s0 + r) * HD + d] = f2bf(acc[mt][nt][r] + bv);
        }
      }
  } else {
#pragma unroll
    for (int mt = 0; mt < 4; mt++)
#pragma unroll
      for (int nt = 0; nt < 4; nt++)
#pragma unroll
        for (int r = 0; r < 4; r++) {
          const int row = brow + wr * 64 + mt * 16 + (lane >> 4) * 4 + r;
          const int col = bcol + wc * 64 + nt * 16 + lrow;
          Cout[(size_t)row * N + col] = acc[mt][nt][r] + bias[col];
        }
  }
}

// ---------------- causal flash attention (pair-balanced, double-buffered) ----
// grid (16, B*H), 256 threads. Block pr handles q-tiles {pr, 31-pr}; K/V staged
// once per jb for both tiles, double-buffered, ONE barrier per tile.
// K fragments hoisted once per tile (shared by both process calls); softmax
// reduces use DPP (VALU) not shfl_xor (LDS pipe is the saturated resource).
__global__ __launch_bounds__(256, 2) void k_attn(const u16* __restrict__ q_ws,
                                                 const u16* __restrict__ k_ws,
                                                 const u16* __restrict__ v_t,
                                                 u16* __restrict__ y) {
  __shared__ u16 Kl[2][64 * 64];     // XOR-swizzled rows (16B blocks), [kv][d]
  __shared__ u16 Vl[2][64 * 64];     // XOR-swizzled rows, [d][kv]
  __shared__ u16 Pl[4][16 * 64];     // per-wave P, XOR-swizzled
  const int tid = threadIdx.x;
  const int w = tid >> 6, lane = tid & 63;
  const int lrow = lane & 15, lk8 = (lane >> 4) * 8;
  const int qrow_t = (lane >> 4) * 4;
  const int pr = blockIdx.x;               // 0..15
  const int tileA = pr, tileB = 31 - pr;   // tileA < tileB, work = const 33
  const int bh = blockIdx.y;
  const size_t base = (size_t)bh * S_LEN * HD;
  const float SC = 0.125f * 1.4426950408889634f;  // D^-0.5 * log2(e)

  bf16x8 qfA[2], qfB[2];
#pragma unroll
  for (int ks = 0; ks < 2; ks++) {
    qfA[ks] = *(const bf16x8*)&q_ws[base + (size_t)(tileA * 64 + w * 16 + lrow) * HD + ks * 32 + lk8];
    qfB[ks] = *(const bf16x8*)&q_ws[base + (size_t)(tileB * 64 + w * 16 + lrow) * HD + ks * 32 + lk8];
  }

  const f32x4 zero = {0.f, 0.f, 0.f, 0.f};
  f32x4 oA[4], oB[4];
#pragma unroll
  for (int dt = 0; dt < 4; dt++) { oA[dt] = zero; oB[dt] = zero; }
  float mA[4], lA[4], mB[4], lB[4];
#pragma unroll
  for (int r = 0; r < 4; r++) { mA[r] = -1e30f; lA[r] = 0.f; mB[r] = -1e30f; lB[r] = 0.f; }

  u16* Pw = &Pl[w][0];

  auto stage = [&](int jb, int buf) {
#pragma unroll
    for (int i = 0; i < 2; i++) {
      const int c = w * 2 + i;
      const int row = c * 8 + (lane >> 3);
      const int blk = (lane & 7) ^ (row & 7);
      gld_lds16(&k_ws[base + (size_t)(jb * 64 + row) * HD + blk * 8],
                (void*)(&Kl[buf][c * 512]));
      gld_lds16(&v_t[base + (size_t)row * S_LEN + jb * 64 + blk * 8],
                (void*)(&Vl[buf][c * 512]));
    }
  };

  // cur: which K/V buffer to read (runtime 0/1 — plain LDS address math).
  auto process = [&](int cur, const bf16x8 (&kf)[2][4], const bf16x8 (&qf)[2],
                     f32x4 (&o)[4], float (&m_run)[4], float (&l_run)[4],
                     bool maskDiag) {
    // S = Q K^T (per wave: 16 q x 64 kv)
    f32x4 sa[4];
#pragma unroll
    for (int nt = 0; nt < 4; nt++) sa[nt] = zero;
    __builtin_amdgcn_s_setprio(1);
#pragma unroll
    for (int ks = 0; ks < 2; ks++)
#pragma unroll
      for (int nt = 0; nt < 4; nt++)
        sa[nt] = __builtin_amdgcn_mfma_f32_16x16x32_bf16(qf[ks], kf[ks][nt], sa[nt], 0, 0, 0);
    __builtin_amdgcn_s_setprio(0);

    float sv[4][4];
#pragma unroll
    for (int nt = 0; nt < 4; nt++)
#pragma unroll
      for (int r = 0; r < 4; r++) {
        float x = sa[nt][r] * SC;            // log2 domain
        if (maskDiag && (nt * 16 + lrow) > (w * 16 + qrow_t + r)) x = -3.0e38f;
        sv[nt][r] = x;
      }

    // online softmax in log2 domain (rows live in 16-lane groups); DPP reduces
#pragma unroll
    for (int r = 0; r < 4; r++) {
      float mx = fmaxf(fmaxf(sv[0][r], sv[1][r]), fmaxf(sv[2][r], sv[3][r]));
      mx = red16_max(mx);
      const float mn = fmaxf(m_run[r], mx);
      const float alpha = fexp2(m_run[r] - mn);
      float sum = 0.f;
#pragma unroll
      for (int nt = 0; nt < 4; nt++) {
        const float p = fexp2(sv[nt][r] - mn);
        sv[nt][r] = p;
        sum += p;
      }
      sum = red16_sum(sum);
      l_run[r] = l_run[r] * alpha + sum;
      m_run[r] = mn;
#pragma unroll
      for (int dt = 0; dt < 4; dt++) o[dt][r] *= alpha;
    }

    // P -> per-wave LDS (bf16 via cvt_pk, swizzled); rows qrow_t+0..3
#pragma unroll
    for (int nt = 0; nt < 4; nt++) {
      const unsigned pk0 = cvt_pk_bf16(sv[nt][0], sv[nt][1]);
      const unsigned pk1 = cvt_pk_bf16(sv[nt][2], sv[nt][3]);
      const int col2 = (nt * 16 + lrow) * 2;
      char* pb = (char*)Pw;
      *(u16*)(pb + (qrow_t + 0) * 128 + (col2 ^ (((qrow_t + 0) & 7) << 4))) = (u16)pk0;
      *(u16*)(pb + (qrow_t + 1) * 128 + (col2 ^ (((qrow_t + 1) & 7) << 4))) = (u16)(pk0 >> 16);
      *(u16*)(pb + (qrow_t + 2) * 128 + (col2 ^ (((qrow_t + 2) & 7) << 4))) = (u16)pk1;
      *(u16*)(pb + (qrow_t + 3) * 128 + (col2 ^ (((qrow_t + 3) & 7) << 4))) = (u16)(pk1 >> 16);
    }

    // O += P @ V
    __builtin_amdgcn_s_setprio(1);
#pragma unroll
    for (int ks = 0; ks < 2; ks++) {
      const int blk = (ks * 4 + (lane >> 4)) ^ (lrow & 7);
      bf16x8 pf = *(const bf16x8*)((const char*)Pw + lrow * 128 + blk * 16);
#pragma unroll
      for (int dt = 0; dt < 4; dt++) {
        const int vr = dt * 16 + lrow;
        const int vblk = (ks * 4 + (lane >> 4)) ^ (vr & 7);
        bf16x8 vf = *(const bf16x8*)&Vl[cur][vr * 64 + vblk * 8];
        o[dt] = __builtin_amdgcn_mfma_f32_16x16x32_bf16(pf, vf, o[dt], 0, 0, 0);
      }
    }
    __builtin_amdgcn_s_setprio(0);
  };

  stage(0, 0);
  __syncthreads();
  for (int jb = 0; jb <= tileB; jb++) {
    const int cur = jb & 1;
    if (jb < tileB) stage(jb + 1, cur ^ 1);
    // Hoist K fragments once per tile — shared by both process calls.
    bf16x8 kf[2][4];
#pragma unroll
    for (int ks = 0; ks < 2; ks++)
#pragma unroll
      for (int nt = 0; nt < 4; nt++) {
        const int kvr = nt * 16 + lrow;
        const int blk = (ks * 4 + (lane >> 4)) ^ (kvr & 7);
        kf[ks][nt] = *(const bf16x8*)&Kl[cur][kvr * 64 + blk * 8];
      }
    process(cur, kf, qfB, oB, mB, lB, jb == tileB);
    if (jb <= tileA) process(cur, kf, qfA, oA, mA, lA, jb == tileA);
    __syncthreads();
  }

  const int b = bh >> 4, h = bh & 15;
#pragma unroll
  for (int r = 0; r < 4; r++) {
    const float invA = 1.0f / lA[r];
    const float invB = 1.0f / lB[r];
    const int qgA = tileA * 64 + w * 16 + qrow_t + r;
    const int qgB = tileB * 64 + w * 16 + qrow_t + r;
#pragma unroll
    for (int dt = 0; dt < 4; dt++) {
      y[((size_t)(b * S_LEN + qgA)) * EMB + h * HD + dt * 16 + lrow] = f2bf(oA[dt][r] * invA);
      y[((size_t)(b * S_LEN + qgB)) * EMB + h * HD + dt * 16 + lrow] = f2bf(oB[dt][r] * invB);
    }
  }
}

extern "C" void kernel_launch(void* const* d_in, const int* in_sizes, int n_in,
                              void* d_out, int out_size, void* d_ws, size_t ws_size,
                              hipStream_t stream) {
  const float* x      = (const float*)d_in[0];
  const float* w_qkv  = (const float*)d_in[1];
  const float* b_qkv  = (const float*)d_in[2];
  const float* w_proj = (const float*)d_in[3];
  const float* b_proj = (const float*)d_in[4];
  float* out = (float*)d_out;

  char* ws = (char*)d_ws;
  u16* wqkvT  = (u16*)(ws);                  // 3072x1024 bf16 (6 MB)
  u16* wprojT = (u16*)(ws + 6291456);        // 1024x1024 bf16 (2 MB)
  u16* xb     = (u16*)(ws + 8388608);        // 8192x1024 bf16 (16 MB), reused as y_att
  u16* q_ws   = (u16*)(ws + 25165824);       // [B,H,S,D] bf16 (16 MB)
  u16* k_ws   = (u16*)(ws + 41943040);       // [B,H,S,D]
  u16* v_t    = (u16*)(ws + 58720256);       // [B,H,D,S] (transposed!)  end: 72 MB
  u16* y_att  = xb;                          // x dead after GEMM1

  k_cvt<<<dim3(1024), dim3(256), 0, stream>>>(x, xb, (8192 * 1024) / 4);
  k_transpose_cvt<<<dim3(48, 16), dim3(256), 0, stream>>>(w_qkv, wqkvT, 1024, 3072);
  k_transpose_cvt<<<dim3(16, 16), dim3(256), 0, stream>>>(w_proj, wprojT, 1024, 1024);
  k_gemm<0><<<dim3(24, 64), dim3(256), 0, stream>>>(xb, wqkvT, b_qkv, nullptr,
                                                    q_ws, k_ws, v_t, 3072, 1024);
  k_attn<<<dim3(16, 64), dim3(256), 0, stream>>>(q_ws, k_ws, v_t, y_att);
  k_gemm<1><<<dim3(8, 64), dim3(256), 0, stream>>>(y_att, wprojT, b_proj, out,
                                                   nullptr, nullptr, nullptr, 1024, 1024);
}

// Round 8
// 201.856 us; speedup vs baseline: 4.5606x; 1.0707x over previous
//
#include <hip/hip_runtime.h>
#include <hip/hip_bf16.h>
#include <stdint.h>

#define S_LEN 2048
#define EMB   1024
#define NH    16
#define HD    64

typedef unsigned short u16;
typedef __attribute__((ext_vector_type(4))) float f32x4;
typedef __attribute__((ext_vector_type(8))) short bf16x8;

typedef __attribute__((address_space(1))) const unsigned char gas_t;
typedef __attribute__((address_space(3))) unsigned char las_t;

static __device__ __forceinline__ void gld_lds16(const void* g, void* l) {
  __builtin_amdgcn_global_load_lds((gas_t*)g, (las_t*)l, 16, 0, 0);
}

static __device__ __forceinline__ u16 f2bf(float f) {
  unsigned int u = __builtin_bit_cast(unsigned int, f);
  u = u + 0x7fffu + ((u >> 16) & 1u);   // RNE; inputs are finite
  return (u16)(u >> 16);
}

// exp2 in one instruction (v_exp_f32 IS 2^x). HW-validated R4/R5.
static __device__ __forceinline__ float fexp2(float x) {
  float r;
  asm("v_exp_f32 %0, %1" : "=v"(r) : "v"(x));
  return r;
}

// pack 2 f32 -> 2 bf16 (RNE); lo = first arg. HW-validated R4/R5.
static __device__ __forceinline__ unsigned cvt_pk_bf16(float lo, float hi) {
  unsigned r;
  asm("v_cvt_pk_bf16_f32 %0, %1, %2" : "=v"(r) : "v"(lo), "v"(hi));
  return r;
}

// Permlane swaps via BUILTINS (not inline asm). R6/R7 NaN root-cause:
// v_permlane*_swap has a VALU->permlane RAW hazard needing compiler-inserted
// wait states; instructions inside one asm blob get no hazard mitigation, so
// the swap read a stale register. Builtins let the backend handle hazards
// (proven combination: inline-asm cvt_pk -> builtin permlane, m214 v22).
// Semantics: p32: new_a=[a0,a1,b0,b1], new_b=[a2,a3,b2,b3] (rows = 16 lanes);
//            p16: new_a=[a0,b0,a2,b2], new_b=[a1,b1,a3,b3].
static __device__ __forceinline__ float red4rows_max(float x) {
  unsigned u = __builtin_bit_cast(unsigned, x);
  auto r = __builtin_amdgcn_permlane32_swap(u, u, false, false);
  float y = fmaxf(__builtin_bit_cast(float, (unsigned)r[0]),
                  __builtin_bit_cast(float, (unsigned)r[1]));
  unsigned v = __builtin_bit_cast(unsigned, y);
  auto r2 = __builtin_amdgcn_permlane16_swap(v, v, false, false);
  return fmaxf(__builtin_bit_cast(float, (unsigned)r2[0]),
               __builtin_bit_cast(float, (unsigned)r2[1]));
}
static __device__ __forceinline__ float red4rows_sum(float x) {
  unsigned u = __builtin_bit_cast(unsigned, x);
  auto r = __builtin_amdgcn_permlane32_swap(u, u, false, false);
  float y = __builtin_bit_cast(float, (unsigned)r[0]) +
            __builtin_bit_cast(float, (unsigned)r[1]);
  unsigned v = __builtin_bit_cast(unsigned, y);
  auto r2 = __builtin_amdgcn_permlane16_swap(v, v, false, false);
  return __builtin_bit_cast(float, (unsigned)r2[0]) +
         __builtin_bit_cast(float, (unsigned)r2[1]);
}

// ---------------- x f32 -> bf16 ----------------
__global__ __launch_bounds__(256) void k_cvt(const float* __restrict__ in,
                                             u16* __restrict__ out, int n4) {
  int i = blockIdx.x * blockDim.x + threadIdx.x;
  int stride = gridDim.x * blockDim.x;
  for (; i < n4; i += stride) {
    float4 f = ((const float4*)in)[i];
    ushort4 o;
    o.x = f2bf(f.x); o.y = f2bf(f.y); o.z = f2bf(f.z); o.w = f2bf(f.w);
    ((ushort4*)out)[i] = o;
  }
}

// ---------------- W [K][N] f32 -> WT [N][K] bf16 ----------------
// grid (N/64, K/64), 256 threads
__global__ __launch_bounds__(256) void k_transpose_cvt(const float* __restrict__ W,
                                                       u16* __restrict__ WT,
                                                       int K, int N) {
  __shared__ u16 tile[64][68];
  const int c0 = blockIdx.x * 64, r0 = blockIdx.y * 64;
  const int t = threadIdx.x;
  const int tr = t >> 4, tc4 = (t & 15) * 4;
#pragma unroll
  for (int i = 0; i < 4; i++) {
    const int r = tr + 16 * i;
    float4 f = *(const float4*)&W[(size_t)(r0 + r) * N + c0 + tc4];
    ushort4 o;
    o.x = f2bf(f.x); o.y = f2bf(f.y); o.z = f2bf(f.z); o.w = f2bf(f.w);
    *(ushort4*)&tile[r][tc4] = o;
  }
  __syncthreads();
  const int oc = t >> 2, or0 = (t & 3) * 16;
  u16 vals[16];
#pragma unroll
  for (int j = 0; j < 16; j++) vals[j] = tile[or0 + j][oc];
  u16* dst = &WT[(size_t)(c0 + oc) * K + r0 + or0];
  *(uint4*)dst = *(const uint4*)&vals[0];
  *(uint4*)(dst + 8) = *(const uint4*)&vals[8];
}

// ---------------- GEMM: C[M,N] = A[M,K](bf16) @ BT[N,K]^T + bias ----------------
// 128x128 tile, BK=32, 4 waves, double-buffered LDS, one barrier per k-step.
// MODE 0: scatter q/k bf16 [B,H,S,D], v bf16 [B,H,D,S] (transposed, vectorized).
// MODE 1: f32 out + bias.
template <int MODE>
__global__ __launch_bounds__(256) void k_gemm(const u16* __restrict__ A,
                                              const u16* __restrict__ BT,
                                              const float* __restrict__ bias,
                                              float* __restrict__ Cout,
                                              u16* __restrict__ q_ws,
                                              u16* __restrict__ k_ws,
                                              u16* __restrict__ v_t,
                                              int N, int K) {
  __shared__ u16 As[2][128 * 32];
  __shared__ u16 Bs[2][128 * 32];
  const int tid = threadIdx.x;
  const int w = tid >> 6, lane = tid & 63;
  const int wr = w >> 1, wc = w & 1;
  const int lrow = lane & 15, lk8 = (lane >> 4) * 8;
  const int brow = blockIdx.y * 128, bcol = blockIdx.x * 128;
  const int srow = lane >> 2;          // 0..15 within chunk
  const int scol = (lane & 3) * 8;     // 0,8,16,24

  const f32x4 zero = {0.f, 0.f, 0.f, 0.f};
  f32x4 acc[4][4];
#pragma unroll
  for (int m = 0; m < 4; m++)
#pragma unroll
    for (int n = 0; n < 4; n++) acc[m][n] = zero;

  auto stage = [&](int kt, int buf) {
#pragma unroll
    for (int i = 0; i < 2; i++) {
      const int c = w * 2 + i;               // chunk 0..7, 1KB each (linear LDS)
      const int row = c * 16 + srow;
      gld_lds16(&A[(size_t)(brow + row) * K + kt + scol], (void*)(&As[buf][c * 512]));
      gld_lds16(&BT[(size_t)(bcol + row) * K + kt + scol], (void*)(&Bs[buf][c * 512]));
    }
  };

  const int NK = K >> 5;
  stage(0, 0);
  __syncthreads();
  for (int it = 0; it < NK; ++it) {
    const int cur = it & 1;
    if (it + 1 < NK) stage((it + 1) << 5, cur ^ 1);
    bf16x8 af[4], bfr[4];
#pragma unroll
    for (int mt = 0; mt < 4; mt++)
      af[mt] = *(const bf16x8*)&As[cur][(wr * 64 + mt * 16 + lrow) * 32 + lk8];
#pragma unroll
    for (int nt = 0; nt < 4; nt++)
      bfr[nt] = *(const bf16x8*)&Bs[cur][(wc * 64 + nt * 16 + lrow) * 32 + lk8];
    __builtin_amdgcn_s_setprio(1);
#pragma unroll
    for (int mt = 0; mt < 4; mt++)
#pragma unroll
      for (int nt = 0; nt < 4; nt++)
        acc[mt][nt] = __builtin_amdgcn_mfma_f32_16x16x32_bf16(af[mt], bfr[nt],
                                                              acc[mt][nt], 0, 0, 0);
    __builtin_amdgcn_s_setprio(0);
    __syncthreads();
  }

  if constexpr (MODE == 0) {
    const int which = bcol >> 10;   // uniform per block (0=q, 1=k, 2=v)
#pragma unroll
    for (int mt = 0; mt < 4; mt++)
#pragma unroll
      for (int nt = 0; nt < 4; nt++) {
        const int col = bcol + wc * 64 + nt * 16 + lrow;
        const int e = col & 1023;
        const int h = e >> 6, d = e & 63;
        const int row0 = brow + wr * 64 + mt * 16 + (lane >> 4) * 4;
        const int b = row0 >> 11, s0 = row0 & 2047;
        const size_t bh = (size_t)(b * NH + h);
        const float bv = bias[col];
        if (which == 2) {
          ushort4 pk;
          pk.x = f2bf(acc[mt][nt][0] + bv);
          pk.y = f2bf(acc[mt][nt][1] + bv);
          pk.z = f2bf(acc[mt][nt][2] + bv);
          pk.w = f2bf(acc[mt][nt][3] + bv);
          *(ushort4*)&v_t[(bh * HD + d) * S_LEN + s0] = pk;
        } else {
          u16* dst = which ? k_ws : q_ws;
#pragma unroll
          for (int r = 0; r < 4; r++)
            dst[(bh * S_LEN + s0 + r) * HD + d] = f2bf(acc[mt][nt][r] + bv);
        }
      }
  } else {
#pragma unroll
    for (int mt = 0; mt < 4; mt++)
#pragma unroll
      for (int nt = 0; nt < 4; nt++)
#pragma unroll
        for (int r = 0; r < 4; r++) {
          const int row = brow + wr * 64 + mt * 16 + (lane >> 4) * 4 + r;
          const int col = bcol + wc * 64 + nt * 16 + lrow;
          Cout[(size_t)row * N + col] = acc[mt][nt][r] + bias[col];
        }
  }
}

// ---------------- causal flash attention ------------------------------------
// grid (16, B*H), 256 threads, pair-balanced {pr, 31-pr}, K/V double-buffered.
// SWAPPED QK^T: sa = mfma(K,Q) -> S[kv][q], q = lane&15, kv = nt*16+g*4+r
// (g = lane>>4). Softmax: in-lane over 16 kv + 2 permlane-swap stages.
// P stays IN REGISTERS: cvt_pk pairs then 8 permlane swaps produce the exact
// PV B-operand (frag[ks] row g = kv 32ks+8g..+7). PV = mfma(V^T, P) -> O[d][q].
// No P LDS buffer at all.
__global__ __launch_bounds__(256, 2) void k_attn(const u16* __restrict__ q_ws,
                                                 const u16* __restrict__ k_ws,
                                                 const u16* __restrict__ v_t,
                                                 u16* __restrict__ y) {
  __shared__ u16 Kl[2][64 * 64];     // XOR-swizzled rows (16B blocks), [kv][d]
  __shared__ u16 Vl[2][64 * 64];     // XOR-swizzled rows, [d][kv]
  const int tid = threadIdx.x;
  const int w = tid >> 6, lane = tid & 63;
  const int lrow = lane & 15, lk8 = (lane >> 4) * 8;
  const int g4 = (lane >> 4) * 4;
  const int pr = blockIdx.x;               // 0..15
  const int tileA = pr, tileB = 31 - pr;   // tileA < tileB, work = const 33
  const int bh = blockIdx.y;
  const size_t base = (size_t)bh * S_LEN * HD;
  const float SC = 0.125f * 1.4426950408889634f;  // D^-0.5 * log2(e)

  bf16x8 qfA[2], qfB[2];
#pragma unroll
  for (int ks = 0; ks < 2; ks++) {
    qfA[ks] = *(const bf16x8*)&q_ws[base + (size_t)(tileA * 64 + w * 16 + lrow) * HD + ks * 32 + lk8];
    qfB[ks] = *(const bf16x8*)&q_ws[base + (size_t)(tileB * 64 + w * 16 + lrow) * HD + ks * 32 + lk8];
  }

  const f32x4 zero = {0.f, 0.f, 0.f, 0.f};
  f32x4 oA[4], oB[4];                 // O[d][q]: d = dt*16 + g4 + r, q = lrow
#pragma unroll
  for (int dt = 0; dt < 4; dt++) { oA[dt] = zero; oB[dt] = zero; }
  float mA = -1e30f, lA = 0.f, mB = -1e30f, lB = 0.f;

  auto stage = [&](int jb, int buf) {
#pragma unroll
    for (int i = 0; i < 2; i++) {
      const int c = w * 2 + i;
      const int row = c * 8 + (lane >> 3);
      const int blk = (lane & 7) ^ (row & 7);
      gld_lds16(&k_ws[base + (size_t)(jb * 64 + row) * HD + blk * 8],
                (void*)(&Kl[buf][c * 512]));
      gld_lds16(&v_t[base + (size_t)row * S_LEN + jb * 64 + blk * 8],
                (void*)(&Vl[buf][c * 512]));
    }
  };

  auto process = [&](int cur, const bf16x8 (&kf)[2][4], const bf16x8 (&qf)[2],
                     f32x4 (&o)[4], float& m_run, float& l_run, bool maskDiag) {
    // S = K Q^T (swapped): sa[nt][r] = S[kv = nt*16+g4+r][q = lrow]
    f32x4 sa[4];
#pragma unroll
    for (int nt = 0; nt < 4; nt++) sa[nt] = zero;
    __builtin_amdgcn_s_setprio(1);
#pragma unroll
    for (int ks = 0; ks < 2; ks++)
#pragma unroll
      for (int nt = 0; nt < 4; nt++)
        sa[nt] = __builtin_amdgcn_mfma_f32_16x16x32_bf16(kf[ks][nt], qf[ks], sa[nt], 0, 0, 0);
    __builtin_amdgcn_s_setprio(0);

    float sv[4][4];
#pragma unroll
    for (int nt = 0; nt < 4; nt++)
#pragma unroll
      for (int r = 0; r < 4; r++) {
        float x = sa[nt][r] * SC;            // log2 domain
        if (maskDiag && (nt * 16 + g4 + r) > (w * 16 + lrow)) x = -3.0e38f;
        sv[nt][r] = x;
      }

    // softmax: in-lane max/sum over 16 kv, then cross-row (4 g-groups)
    float mx = fmaxf(fmaxf(fmaxf(sv[0][0], sv[0][1]), fmaxf(sv[0][2], sv[0][3])),
                     fmaxf(fmaxf(sv[1][0], sv[1][1]), fmaxf(sv[1][2], sv[1][3])));
    mx = fmaxf(mx,
               fmaxf(fmaxf(fmaxf(sv[2][0], sv[2][1]), fmaxf(sv[2][2], sv[2][3])),
                     fmaxf(fmaxf(sv[3][0], sv[3][1]), fmaxf(sv[3][2], sv[3][3]))));
    mx = red4rows_max(mx);
    const float mn = fmaxf(m_run, mx);
    const float alpha = fexp2(m_run - mn);
    float sum = 0.f;
#pragma unroll
    for (int nt = 0; nt < 4; nt++)
#pragma unroll
      for (int r = 0; r < 4; r++) {
        const float p = fexp2(sv[nt][r] - mn);
        sv[nt][r] = p;
        sum += p;
      }
    sum = red4rows_sum(sum);
    l_run = l_run * alpha + sum;
    m_run = mn;
#pragma unroll
    for (int dt = 0; dt < 4; dt++) o[dt] *= alpha;

    // P -> PV B-operand entirely in registers (builtin permlane swaps).
    // pk[nt][h] holds (P[kv=nt*16+g4+2h][q], P[kv+1][q]).
    unsigned pk[4][2];
#pragma unroll
    for (int nt = 0; nt < 4; nt++) {
      pk[nt][0] = cvt_pk_bf16(sv[nt][0], sv[nt][1]);
      pk[nt][1] = cvt_pk_bf16(sv[nt][2], sv[nt][3]);
    }
    // p32(a,b) -> A=[a_g0,a_g1,b_g0,b_g1], B=[a_g2,a_g3,b_g2,b_g3];
    // p16(A,B) -> C=[A0,B0,A2,B2] = target dword (rows g: kv base 8g),
    //             D=[A1,B1,A3,B3] = target dword+2.
    union { unsigned u[4]; bf16x8 v; } c0, c1;
    {
      auto r0 = __builtin_amdgcn_permlane32_swap(pk[0][0], pk[1][0], false, false);
      auto s0 = __builtin_amdgcn_permlane16_swap(r0[0], r0[1], false, false);
      auto r1 = __builtin_amdgcn_permlane32_swap(pk[0][1], pk[1][1], false, false);
      auto s1 = __builtin_amdgcn_permlane16_swap(r1[0], r1[1], false, false);
      c0.u[0] = s0[0]; c0.u[1] = s1[0]; c0.u[2] = s0[1]; c0.u[3] = s1[1];
      auto r2 = __builtin_amdgcn_permlane32_swap(pk[2][0], pk[3][0], false, false);
      auto s2 = __builtin_amdgcn_permlane16_swap(r2[0], r2[1], false, false);
      auto r3 = __builtin_amdgcn_permlane32_swap(pk[2][1], pk[3][1], false, false);
      auto s3 = __builtin_amdgcn_permlane16_swap(r3[0], r3[1], false, false);
      c1.u[0] = s2[0]; c1.u[1] = s3[0]; c1.u[2] = s2[1]; c1.u[3] = s3[1];
    }
    bf16x8 pfrag[2] = {c0.v, c1.v};

    // O += V^T P : o[dt] rows d = dt*16+g4+r, col q = lrow
    __builtin_amdgcn_s_setprio(1);
#pragma unroll
    for (int ks = 0; ks < 2; ks++)
#pragma unroll
      for (int dt = 0; dt < 4; dt++) {
        const int vr = dt * 16 + lrow;
        const int vblk = (ks * 4 + (lane >> 4)) ^ (vr & 7);
        bf16x8 vf = *(const bf16x8*)&Vl[cur][vr * 64 + vblk * 8];
        o[dt] = __builtin_amdgcn_mfma_f32_16x16x32_bf16(vf, pfrag[ks], o[dt], 0, 0, 0);
      }
    __builtin_amdgcn_s_setprio(0);
  };

  stage(0, 0);
  __syncthreads();
  for (int jb = 0; jb <= tileB; jb++) {
    const int cur = jb & 1;
    if (jb < tileB) stage(jb + 1, cur ^ 1);
    // Hoist K fragments once per tile — identical lane layout for A-operand.
    bf16x8 kf[2][4];
#pragma unroll
    for (int ks = 0; ks < 2; ks++)
#pragma unroll
      for (int nt = 0; nt < 4; nt++) {
        const int kvr = nt * 16 + lrow;
        const int blk = (ks * 4 + (lane >> 4)) ^ (kvr & 7);
        kf[ks][nt] = *(const bf16x8*)&Kl[cur][kvr * 64 + blk * 8];
      }
    process(cur, kf, qfB, oB, mB, lB, jb == tileB);
    if (jb <= tileA) process(cur, kf, qfA, oA, mA, lA, jb == tileA);
    __syncthreads();
  }

  const int b = bh >> 4, h = bh & 15;
  const float invA = 1.0f / lA;
  const float invB = 1.0f / lB;
  const int qgA = tileA * 64 + w * 16 + lrow;
  const int qgB = tileB * 64 + w * 16 + lrow;
#pragma unroll
  for (int dt = 0; dt < 4; dt++) {
    ushort4 sA, sB;
    sA.x = f2bf(oA[dt][0] * invA); sA.y = f2bf(oA[dt][1] * invA);
    sA.z = f2bf(oA[dt][2] * invA); sA.w = f2bf(oA[dt][3] * invA);
    sB.x = f2bf(oB[dt][0] * invB); sB.y = f2bf(oB[dt][1] * invB);
    sB.z = f2bf(oB[dt][2] * invB); sB.w = f2bf(oB[dt][3] * invB);
    *(ushort4*)&y[(size_t)(b * S_LEN + qgA) * EMB + h * HD + dt * 16 + g4] = sA;
    *(ushort4*)&y[(size_t)(b * S_LEN + qgB) * EMB + h * HD + dt * 16 + g4] = sB;
  }
}

extern "C" void kernel_launch(void* const* d_in, const int* in_sizes, int n_in,
                              void* d_out, int out_size, void* d_ws, size_t ws_size,
                              hipStream_t stream) {
  const float* x      = (const float*)d_in[0];
  const float* w_qkv  = (const float*)d_in[1];
  const float* b_qkv  = (const float*)d_in[2];
  const float* w_proj = (const float*)d_in[3];
  const float* b_proj = (const float*)d_in[4];
  float* out = (float*)d_out;

  char* ws = (char*)d_ws;
  u16* wqkvT  = (u16*)(ws);                  // 3072x1024 bf16 (6 MB)
  u16* wprojT = (u16*)(ws + 6291456);        // 1024x1024 bf16 (2 MB)
  u16* xb     = (u16*)(ws + 8388608);        // 8192x1024 bf16 (16 MB), reused as y_att
  u16* q_ws   = (u16*)(ws + 25165824);       // [B,H,S,D] bf16 (16 MB)
  u16* k_ws   = (u16*)(ws + 41943040);       // [B,H,S,D]
  u16* v_t    = (u16*)(ws + 58720256);       // [B,H,D,S] (transposed!)  end: 72 MB
  u16* y_att  = xb;                          // x dead after GEMM1

  k_cvt<<<dim3(1024), dim3(256), 0, stream>>>(x, xb, (8192 * 1024) / 4);
  k_transpose_cvt<<<dim3(48, 16), dim3(256), 0, stream>>>(w_qkv, wqkvT, 1024, 3072);
  k_transpose_cvt<<<dim3(16, 16), dim3(256), 0, stream>>>(w_proj, wprojT, 1024, 1024);
  k_gemm<0><<<dim3(24, 64), dim3(256), 0, stream>>>(xb, wqkvT, b_qkv, nullptr,
                                                    q_ws, k_ws, v_t, 3072, 1024);
  k_attn<<<dim3(16, 64), dim3(256), 0, stream>>>(q_ws, k_ws, v_t, y_att);
  k_gemm<1><<<dim3(8, 64), dim3(256), 0, stream>>>(y_att, wprojT, b_proj, out,
                                                   nullptr, nullptr, nullptr, 1024, 1024);
}

// Round 9
// 197.510 us; speedup vs baseline: 4.6609x; 1.0220x over previous
//
#include <hip/hip_runtime.h>
#include <hip/hip_bf16.h>
#include <stdint.h>

#define S_LEN 2048
#define EMB   1024
#define NH    16
#define HD    64

typedef unsigned short u16;
typedef __attribute__((ext_vector_type(4))) float f32x4;
typedef __attribute__((ext_vector_type(8))) short bf16x8;

typedef __attribute__((address_space(1))) const unsigned char gas_t;
typedef __attribute__((address_space(3))) unsigned char las_t;

static __device__ __forceinline__ void gld_lds16(const void* g, void* l) {
  __builtin_amdgcn_global_load_lds((gas_t*)g, (las_t*)l, 16, 0, 0);
}

static __device__ __forceinline__ u16 f2bf(float f) {
  unsigned int u = __builtin_bit_cast(unsigned int, f);
  u = u + 0x7fffu + ((u >> 16) & 1u);   // RNE; inputs are finite
  return (u16)(u >> 16);
}

// exp2 in one instruction (v_exp_f32 IS 2^x). HW-validated R4/R5.
static __device__ __forceinline__ float fexp2(float x) {
  float r;
  asm("v_exp_f32 %0, %1" : "=v"(r) : "v"(x));
  return r;
}

// pack 2 f32 -> 2 bf16 (RNE); lo = first arg. HW-validated R4/R5.
static __device__ __forceinline__ unsigned cvt_pk_bf16(float lo, float hi) {
  unsigned r;
  asm("v_cvt_pk_bf16_f32 %0, %1, %2" : "=v"(r) : "v"(lo), "v"(hi));
  return r;
}

// Permlane swaps via BUILTINS (not inline asm) — R6/R7 lesson: the
// VALU->permlane RAW hazard is only mitigated for compiler-known instrs.
// Semantics: p32: new_a=[a0,a1,b0,b1], new_b=[a2,a3,b2,b3] (rows = 16 lanes);
//            p16: new_a=[a0,b0,a2,b2], new_b=[a1,b1,a3,b3].
static __device__ __forceinline__ float red4rows_max(float x) {
  unsigned u = __builtin_bit_cast(unsigned, x);
  auto r = __builtin_amdgcn_permlane32_swap(u, u, false, false);
  float y = fmaxf(__builtin_bit_cast(float, (unsigned)r[0]),
                  __builtin_bit_cast(float, (unsigned)r[1]));
  unsigned v = __builtin_bit_cast(unsigned, y);
  auto r2 = __builtin_amdgcn_permlane16_swap(v, v, false, false);
  return fmaxf(__builtin_bit_cast(float, (unsigned)r2[0]),
               __builtin_bit_cast(float, (unsigned)r2[1]));
}
static __device__ __forceinline__ float red4rows_sum(float x) {
  unsigned u = __builtin_bit_cast(unsigned, x);
  auto r = __builtin_amdgcn_permlane32_swap(u, u, false, false);
  float y = __builtin_bit_cast(float, (unsigned)r[0]) +
            __builtin_bit_cast(float, (unsigned)r[1]);
  unsigned v = __builtin_bit_cast(unsigned, y);
  auto r2 = __builtin_amdgcn_permlane16_swap(v, v, false, false);
  return __builtin_bit_cast(float, (unsigned)r2[0]) +
         __builtin_bit_cast(float, (unsigned)r2[1]);
}

// ---------------- x f32 -> bf16 ----------------
__global__ __launch_bounds__(256) void k_cvt(const float* __restrict__ in,
                                             u16* __restrict__ out, int n4) {
  int i = blockIdx.x * blockDim.x + threadIdx.x;
  int stride = gridDim.x * blockDim.x;
  for (; i < n4; i += stride) {
    float4 f = ((const float4*)in)[i];
    ushort4 o;
    o.x = f2bf(f.x); o.y = f2bf(f.y); o.z = f2bf(f.z); o.w = f2bf(f.w);
    ((ushort4*)out)[i] = o;
  }
}

// ---------------- W [K][N] f32 -> WT [N][K] bf16 ----------------
// grid (N/64, K/64), 256 threads
__global__ __launch_bounds__(256) void k_transpose_cvt(const float* __restrict__ W,
                                                       u16* __restrict__ WT,
                                                       int K, int N) {
  __shared__ u16 tile[64][68];
  const int c0 = blockIdx.x * 64, r0 = blockIdx.y * 64;
  const int t = threadIdx.x;
  const int tr = t >> 4, tc4 = (t & 15) * 4;
#pragma unroll
  for (int i = 0; i < 4; i++) {
    const int r = tr + 16 * i;
    float4 f = *(const float4*)&W[(size_t)(r0 + r) * N + c0 + tc4];
    ushort4 o;
    o.x = f2bf(f.x); o.y = f2bf(f.y); o.z = f2bf(f.z); o.w = f2bf(f.w);
    *(ushort4*)&tile[r][tc4] = o;
  }
  __syncthreads();
  const int oc = t >> 2, or0 = (t & 3) * 16;
  u16 vals[16];
#pragma unroll
  for (int j = 0; j < 16; j++) vals[j] = tile[or0 + j][oc];
  u16* dst = &WT[(size_t)(c0 + oc) * K + r0 + or0];
  *(uint4*)dst = *(const uint4*)&vals[0];
  *(uint4*)(dst + 8) = *(const uint4*)&vals[8];
}

// ---------------- GEMM: C[M,N] = A[M,K](bf16) @ BT[N,K]^T + bias ----------------
// 128x128 tile, BK=32, 4 waves, double-buffered LDS, one barrier per k-step.
// MODE 0: scatter q/k bf16 [B,H,S,D], v bf16 [B,H,D,S] (transposed, vectorized).
// MODE 1: f32 out + bias.
template <int MODE>
__global__ __launch_bounds__(256) void k_gemm(const u16* __restrict__ A,
                                              const u16* __restrict__ BT,
                                              const float* __restrict__ bias,
                                              float* __restrict__ Cout,
                                              u16* __restrict__ q_ws,
                                              u16* __restrict__ k_ws,
                                              u16* __restrict__ v_t,
                                              int N, int K) {
  __shared__ u16 As[2][128 * 32];
  __shared__ u16 Bs[2][128 * 32];
  const int tid = threadIdx.x;
  const int w = tid >> 6, lane = tid & 63;
  const int wr = w >> 1, wc = w & 1;
  const int lrow = lane & 15, lk8 = (lane >> 4) * 8;
  const int brow = blockIdx.y * 128, bcol = blockIdx.x * 128;
  const int srow = lane >> 2;          // 0..15 within chunk
  const int scol = (lane & 3) * 8;     // 0,8,16,24

  const f32x4 zero = {0.f, 0.f, 0.f, 0.f};
  f32x4 acc[4][4];
#pragma unroll
  for (int m = 0; m < 4; m++)
#pragma unroll
    for (int n = 0; n < 4; n++) acc[m][n] = zero;

  auto stage = [&](int kt, int buf) {
#pragma unroll
    for (int i = 0; i < 2; i++) {
      const int c = w * 2 + i;               // chunk 0..7, 1KB each (linear LDS)
      const int row = c * 16 + srow;
      gld_lds16(&A[(size_t)(brow + row) * K + kt + scol], (void*)(&As[buf][c * 512]));
      gld_lds16(&BT[(size_t)(bcol + row) * K + kt + scol], (void*)(&Bs[buf][c * 512]));
    }
  };

  const int NK = K >> 5;
  stage(0, 0);
  __syncthreads();
  for (int it = 0; it < NK; ++it) {
    const int cur = it & 1;
    if (it + 1 < NK) stage((it + 1) << 5, cur ^ 1);
    bf16x8 af[4], bfr[4];
#pragma unroll
    for (int mt = 0; mt < 4; mt++)
      af[mt] = *(const bf16x8*)&As[cur][(wr * 64 + mt * 16 + lrow) * 32 + lk8];
#pragma unroll
    for (int nt = 0; nt < 4; nt++)
      bfr[nt] = *(const bf16x8*)&Bs[cur][(wc * 64 + nt * 16 + lrow) * 32 + lk8];
    __builtin_amdgcn_s_setprio(1);
#pragma unroll
    for (int mt = 0; mt < 4; mt++)
#pragma unroll
      for (int nt = 0; nt < 4; nt++)
        acc[mt][nt] = __builtin_amdgcn_mfma_f32_16x16x32_bf16(af[mt], bfr[nt],
                                                              acc[mt][nt], 0, 0, 0);
    __builtin_amdgcn_s_setprio(0);
    __syncthreads();
  }

  if constexpr (MODE == 0) {
    const int which = bcol >> 10;   // uniform per block (0=q, 1=k, 2=v)
#pragma unroll
    for (int mt = 0; mt < 4; mt++)
#pragma unroll
      for (int nt = 0; nt < 4; nt++) {
        const int col = bcol + wc * 64 + nt * 16 + lrow;
        const int e = col & 1023;
        const int h = e >> 6, d = e & 63;
        const int row0 = brow + wr * 64 + mt * 16 + (lane >> 4) * 4;
        const int b = row0 >> 11, s0 = row0 & 2047;
        const size_t bh = (size_t)(b * NH + h);
        const float bv = bias[col];
        if (which == 2) {
          ushort4 pk;
          pk.x = f2bf(acc[mt][nt][0] + bv);
          pk.y = f2bf(acc[mt][nt][1] + bv);
          pk.z = f2bf(acc[mt][nt][2] + bv);
          pk.w = f2bf(acc[mt][nt][3] + bv);
          *(ushort4*)&v_t[(bh * HD + d) * S_LEN + s0] = pk;
        } else {
          u16* dst = which ? k_ws : q_ws;
#pragma unroll
          for (int r = 0; r < 4; r++)
            dst[(bh * S_LEN + s0 + r) * HD + d] = f2bf(acc[mt][nt][r] + bv);
        }
      }
  } else {
#pragma unroll
    for (int mt = 0; mt < 4; mt++)
#pragma unroll
      for (int nt = 0; nt < 4; nt++)
#pragma unroll
        for (int r = 0; r < 4; r++) {
          const int row = brow + wr * 64 + mt * 16 + (lane >> 4) * 4 + r;
          const int col = bcol + wc * 64 + nt * 16 + lrow;
          Cout[(size_t)row * N + col] = acc[mt][nt][r] + bias[col];
        }
  }
}

// ---------------- causal flash attention ------------------------------------
// grid (16, B*H), 256 threads, pair-balanced {pr, 31-pr}, K/V double-buffered.
// SWAPPED QK^T -> S[kv][q]; softmax in-lane + 2 permlane stages; P in
// registers via cvt_pk + permlane routing; PV = mfma(V^T, P) -> O[d][q].
// R9: K AND V fragments hoisted once per tile (shared by both process calls);
// causal mask under a uniform branch (2 of 33 calls); defer-max THR=8.
__global__ __launch_bounds__(256, 2) void k_attn(const u16* __restrict__ q_ws,
                                                 const u16* __restrict__ k_ws,
                                                 const u16* __restrict__ v_t,
                                                 u16* __restrict__ y) {
  __shared__ u16 Kl[2][64 * 64];     // XOR-swizzled rows (16B blocks), [kv][d]
  __shared__ u16 Vl[2][64 * 64];     // XOR-swizzled rows, [d][kv]
  const int tid = threadIdx.x;
  const int w = tid >> 6, lane = tid & 63;
  const int lrow = lane & 15, lk8 = (lane >> 4) * 8;
  const int g4 = (lane >> 4) * 4;
  const int pr = blockIdx.x;               // 0..15
  const int tileA = pr, tileB = 31 - pr;   // tileA < tileB, work = const 33
  const int bh = blockIdx.y;
  const size_t base = (size_t)bh * S_LEN * HD;
  const float SC = 0.125f * 1.4426950408889634f;  // D^-0.5 * log2(e)

  bf16x8 qfA[2], qfB[2];
#pragma unroll
  for (int ks = 0; ks < 2; ks++) {
    qfA[ks] = *(const bf16x8*)&q_ws[base + (size_t)(tileA * 64 + w * 16 + lrow) * HD + ks * 32 + lk8];
    qfB[ks] = *(const bf16x8*)&q_ws[base + (size_t)(tileB * 64 + w * 16 + lrow) * HD + ks * 32 + lk8];
  }

  const f32x4 zero = {0.f, 0.f, 0.f, 0.f};
  f32x4 oA[4], oB[4];                 // O[d][q]: d = dt*16 + g4 + r, q = lrow
#pragma unroll
  for (int dt = 0; dt < 4; dt++) { oA[dt] = zero; oB[dt] = zero; }
  float mA = -1e30f, lA = 0.f, mB = -1e30f, lB = 0.f;

  auto stage = [&](int jb, int buf) {
#pragma unroll
    for (int i = 0; i < 2; i++) {
      const int c = w * 2 + i;
      const int row = c * 8 + (lane >> 3);
      const int blk = (lane & 7) ^ (row & 7);
      gld_lds16(&k_ws[base + (size_t)(jb * 64 + row) * HD + blk * 8],
                (void*)(&Kl[buf][c * 512]));
      gld_lds16(&v_t[base + (size_t)row * S_LEN + jb * 64 + blk * 8],
                (void*)(&Vl[buf][c * 512]));
    }
  };

  auto process = [&](const bf16x8 (&kf)[2][4], const bf16x8 (&vf)[2][4],
                     const bf16x8 (&qf)[2], f32x4 (&o)[4], float& m_run,
                     float& l_run, bool maskDiag) {
    // S = K Q^T (swapped): sa[nt][r] = S[kv = nt*16+g4+r][q = lrow]
    f32x4 sa[4];
#pragma unroll
    for (int nt = 0; nt < 4; nt++) sa[nt] = zero;
    __builtin_amdgcn_s_setprio(1);
#pragma unroll
    for (int ks = 0; ks < 2; ks++)
#pragma unroll
      for (int nt = 0; nt < 4; nt++)
        sa[nt] = __builtin_amdgcn_mfma_f32_16x16x32_bf16(kf[ks][nt], qf[ks], sa[nt], 0, 0, 0);
    __builtin_amdgcn_s_setprio(0);

    // scale (+ causal mask only on the 2/33 diagonal calls; uniform branch)
    float sv[4][4];
    if (maskDiag) {
#pragma unroll
      for (int nt = 0; nt < 4; nt++)
#pragma unroll
        for (int r = 0; r < 4; r++) {
          float x = sa[nt][r] * SC;
          if ((nt * 16 + g4 + r) > (w * 16 + lrow)) x = -3.0e38f;
          sv[nt][r] = x;
        }
    } else {
#pragma unroll
      for (int nt = 0; nt < 4; nt++)
#pragma unroll
        for (int r = 0; r < 4; r++) sv[nt][r] = sa[nt][r] * SC;
    }

    // softmax (log2 domain): in-lane max over 16 kv, then cross-row merge
    float mx = fmaxf(fmaxf(fmaxf(sv[0][0], sv[0][1]), fmaxf(sv[0][2], sv[0][3])),
                     fmaxf(fmaxf(sv[1][0], sv[1][1]), fmaxf(sv[1][2], sv[1][3])));
    mx = fmaxf(mx,
               fmaxf(fmaxf(fmaxf(sv[2][0], sv[2][1]), fmaxf(sv[2][2], sv[2][3])),
                     fmaxf(fmaxf(sv[3][0], sv[3][1]), fmaxf(sv[3][2], sv[3][3]))));
    mx = red4rows_max(mx);
    // defer-max (T13): skip rescale when max growth <= 8 (P bounded by 2^8)
    const bool nogrow = __all(mx <= m_run + 8.0f);
    float mn = m_run;
    if (!nogrow) {
      mn = fmaxf(m_run, mx);
      const float alpha = fexp2(m_run - mn);
      l_run *= alpha;
#pragma unroll
      for (int dt = 0; dt < 4; dt++) o[dt] *= alpha;
      m_run = mn;
    }
    float sum = 0.f;
#pragma unroll
    for (int nt = 0; nt < 4; nt++)
#pragma unroll
      for (int r = 0; r < 4; r++) {
        const float p = fexp2(sv[nt][r] - mn);
        sv[nt][r] = p;
        sum += p;
      }
    sum = red4rows_sum(sum);
    l_run += sum;

    // P -> PV B-operand entirely in registers (builtin permlane swaps).
    unsigned pk[4][2];
#pragma unroll
    for (int nt = 0; nt < 4; nt++) {
      pk[nt][0] = cvt_pk_bf16(sv[nt][0], sv[nt][1]);
      pk[nt][1] = cvt_pk_bf16(sv[nt][2], sv[nt][3]);
    }
    union { unsigned u[4]; bf16x8 v; } c0, c1;
    {
      auto r0 = __builtin_amdgcn_permlane32_swap(pk[0][0], pk[1][0], false, false);
      auto s0 = __builtin_amdgcn_permlane16_swap(r0[0], r0[1], false, false);
      auto r1 = __builtin_amdgcn_permlane32_swap(pk[0][1], pk[1][1], false, false);
      auto s1 = __builtin_amdgcn_permlane16_swap(r1[0], r1[1], false, false);
      c0.u[0] = s0[0]; c0.u[1] = s1[0]; c0.u[2] = s0[1]; c0.u[3] = s1[1];
      auto r2 = __builtin_amdgcn_permlane32_swap(pk[2][0], pk[3][0], false, false);
      auto s2 = __builtin_amdgcn_permlane16_swap(r2[0], r2[1], false, false);
      auto r3 = __builtin_amdgcn_permlane32_swap(pk[2][1], pk[3][1], false, false);
      auto s3 = __builtin_amdgcn_permlane16_swap(r3[0], r3[1], false, false);
      c1.u[0] = s2[0]; c1.u[1] = s3[0]; c1.u[2] = s2[1]; c1.u[3] = s3[1];
    }
    bf16x8 pfrag[2] = {c0.v, c1.v};

    // O += V^T P : o[dt] rows d = dt*16+g4+r, col q = lrow
    __builtin_amdgcn_s_setprio(1);
#pragma unroll
    for (int ks = 0; ks < 2; ks++)
#pragma unroll
      for (int dt = 0; dt < 4; dt++)
        o[dt] = __builtin_amdgcn_mfma_f32_16x16x32_bf16(vf[ks][dt], pfrag[ks], o[dt], 0, 0, 0);
    __builtin_amdgcn_s_setprio(0);
  };

  stage(0, 0);
  __syncthreads();
  for (int jb = 0; jb <= tileB; jb++) {
    const int cur = jb & 1;
    if (jb < tileB) stage(jb + 1, cur ^ 1);
    // Hoist K AND V fragments once per tile — shared by both process calls.
    bf16x8 kf[2][4], vf[2][4];
#pragma unroll
    for (int ks = 0; ks < 2; ks++)
#pragma unroll
      for (int nt = 0; nt < 4; nt++) {
        const int kvr = nt * 16 + lrow;
        const int blk = (ks * 4 + (lane >> 4)) ^ (kvr & 7);
        kf[ks][nt] = *(const bf16x8*)&Kl[cur][kvr * 64 + blk * 8];
        vf[ks][nt] = *(const bf16x8*)&Vl[cur][kvr * 64 + blk * 8];
      }
    process(kf, vf, qfB, oB, mB, lB, jb == tileB);
    if (jb <= tileA) process(kf, vf, qfA, oA, mA, lA, jb == tileA);
    __syncthreads();
  }

  const int b = bh >> 4, h = bh & 15;
  const float invA = 1.0f / lA;
  const float invB = 1.0f / lB;
  const int qgA = tileA * 64 + w * 16 + lrow;
  const int qgB = tileB * 64 + w * 16 + lrow;
#pragma unroll
  for (int dt = 0; dt < 4; dt++) {
    ushort4 sA, sB;
    sA.x = f2bf(oA[dt][0] * invA); sA.y = f2bf(oA[dt][1] * invA);
    sA.z = f2bf(oA[dt][2] * invA); sA.w = f2bf(oA[dt][3] * invA);
    sB.x = f2bf(oB[dt][0] * invB); sB.y = f2bf(oB[dt][1] * invB);
    sB.z = f2bf(oB[dt][2] * invB); sB.w = f2bf(oB[dt][3] * invB);
    *(ushort4*)&y[(size_t)(b * S_LEN + qgA) * EMB + h * HD + dt * 16 + g4] = sA;
    *(ushort4*)&y[(size_t)(b * S_LEN + qgB) * EMB + h * HD + dt * 16 + g4] = sB;
  }
}

extern "C" void kernel_launch(void* const* d_in, const int* in_sizes, int n_in,
                              void* d_out, int out_size, void* d_ws, size_t ws_size,
                              hipStream_t stream) {
  const float* x      = (const float*)d_in[0];
  const float* w_qkv  = (const float*)d_in[1];
  const float* b_qkv  = (const float*)d_in[2];
  const float* w_proj = (const float*)d_in[3];
  const float* b_proj = (const float*)d_in[4];
  float* out = (float*)d_out;

  char* ws = (char*)d_ws;
  u16* wqkvT  = (u16*)(ws);                  // 3072x1024 bf16 (6 MB)
  u16* wprojT = (u16*)(ws + 6291456);        // 1024x1024 bf16 (2 MB)
  u16* xb     = (u16*)(ws + 8388608);        // 8192x1024 bf16 (16 MB), reused as y_att
  u16* q_ws   = (u16*)(ws + 25165824);       // [B,H,S,D] bf16 (16 MB)
  u16* k_ws   = (u16*)(ws + 41943040);       // [B,H,S,D]
  u16* v_t    = (u16*)(ws + 58720256);       // [B,H,D,S] (transposed!)  end: 72 MB
  u16* y_att  = xb;                          // x dead after GEMM1

  k_cvt<<<dim3(1024), dim3(256), 0, stream>>>(x, xb, (8192 * 1024) / 4);
  k_transpose_cvt<<<dim3(48, 16), dim3(256), 0, stream>>>(w_qkv, wqkvT, 1024, 3072);
  k_transpose_cvt<<<dim3(16, 16), dim3(256), 0, stream>>>(w_proj, wprojT, 1024, 1024);
  k_gemm<0><<<dim3(24, 64), dim3(256), 0, stream>>>(xb, wqkvT, b_qkv, nullptr,
                                                    q_ws, k_ws, v_t, 3072, 1024);
  k_attn<<<dim3(16, 64), dim3(256), 0, stream>>>(q_ws, k_ws, v_t, y_att);
  k_gemm<1><<<dim3(8, 64), dim3(256), 0, stream>>>(y_att, wprojT, b_proj, out,
                                                   nullptr, nullptr, nullptr, 1024, 1024);
}

// Round 10
// 193.621 us; speedup vs baseline: 4.7545x; 1.0201x over previous
//
#include <hip/hip_runtime.h>
#include <hip/hip_bf16.h>
#include <stdint.h>

#define S_LEN 2048
#define EMB   1024
#define NH    16
#define HD    64

typedef unsigned short u16;
typedef __attribute__((ext_vector_type(2))) float f32x2;
typedef __attribute__((ext_vector_type(4))) float f32x4;
typedef __attribute__((ext_vector_type(8))) short bf16x8;

typedef __attribute__((address_space(1))) const unsigned char gas_t;
typedef __attribute__((address_space(3))) unsigned char las_t;

static __device__ __forceinline__ void gld_lds16(const void* g, void* l) {
  __builtin_amdgcn_global_load_lds((gas_t*)g, (las_t*)l, 16, 0, 0);
}

static __device__ __forceinline__ u16 f2bf(float f) {
  unsigned int u = __builtin_bit_cast(unsigned int, f);
  u = u + 0x7fffu + ((u >> 16) & 1u);   // RNE; inputs are finite
  return (u16)(u >> 16);
}

// exp2 in one instruction (v_exp_f32 IS 2^x). HW-validated R4/R5.
static __device__ __forceinline__ float fexp2(float x) {
  float r;
  asm("v_exp_f32 %0, %1" : "=v"(r) : "v"(x));
  return r;
}

// pack 2 f32 -> 2 bf16 (RNE); lo = first arg. HW-validated R4/R5.
static __device__ __forceinline__ unsigned cvt_pk_bf16(float lo, float hi) {
  unsigned r;
  asm("v_cvt_pk_bf16_f32 %0, %1, %2" : "=v"(r) : "v"(lo), "v"(hi));
  return r;
}

// packed f32 add (CDNA2+ V_PK_ADD_F32; plain VALU, no cross-lane hazard).
static __device__ __forceinline__ f32x2 pk_add(f32x2 a, f32x2 b) {
  f32x2 r;
  asm("v_pk_add_f32 %0, %1, %2" : "=v"(r) : "v"(a), "v"(b));
  return r;
}

// Permlane swaps via BUILTINS (not inline asm) — R6/R7 lesson: the
// VALU->permlane RAW hazard is only mitigated for compiler-known instrs.
static __device__ __forceinline__ float red4rows_max(float x) {
  unsigned u = __builtin_bit_cast(unsigned, x);
  auto r = __builtin_amdgcn_permlane32_swap(u, u, false, false);
  float y = fmaxf(__builtin_bit_cast(float, (unsigned)r[0]),
                  __builtin_bit_cast(float, (unsigned)r[1]));
  unsigned v = __builtin_bit_cast(unsigned, y);
  auto r2 = __builtin_amdgcn_permlane16_swap(v, v, false, false);
  return fmaxf(__builtin_bit_cast(float, (unsigned)r2[0]),
               __builtin_bit_cast(float, (unsigned)r2[1]));
}
static __device__ __forceinline__ float red4rows_sum(float x) {
  unsigned u = __builtin_bit_cast(unsigned, x);
  auto r = __builtin_amdgcn_permlane32_swap(u, u, false, false);
  float y = __builtin_bit_cast(float, (unsigned)r[0]) +
            __builtin_bit_cast(float, (unsigned)r[1]);
  unsigned v = __builtin_bit_cast(unsigned, y);
  auto r2 = __builtin_amdgcn_permlane16_swap(v, v, false, false);
  return __builtin_bit_cast(float, (unsigned)r2[0]) +
         __builtin_bit_cast(float, (unsigned)r2[1]);
}

// ---------------- fused preprocessing: x->bf16 + both weight transposes -----
// grid 2048 x 256: [0,1024) cvt, [1024,1792) w_qkv T, [1792,2048) w_proj T.
__global__ __launch_bounds__(256) void k_prep(const float* __restrict__ x,
                                              u16* __restrict__ xb,
                                              const float* __restrict__ w_qkv,
                                              u16* __restrict__ wqkvT,
                                              const float* __restrict__ w_proj,
                                              u16* __restrict__ wprojT) {
  __shared__ u16 tile[64][68];
  const int bid = blockIdx.x;
  const int t = threadIdx.x;
  if (bid < 1024) {
    const int n4 = (8192 * 1024) / 4;
    int i = bid * 256 + t;
    for (; i < n4; i += 1024 * 256) {
      float4 f = ((const float4*)x)[i];
      ushort4 o;
      o.x = f2bf(f.x); o.y = f2bf(f.y); o.z = f2bf(f.z); o.w = f2bf(f.w);
      ((ushort4*)xb)[i] = o;
    }
    return;
  }
  const float* W;
  u16* WT;
  int c0, r0, K, N;
  if (bid < 1792) {
    const int idx = bid - 1024;            // 48 x 16 blocks
    W = w_qkv; WT = wqkvT; K = 1024; N = 3072;
    c0 = (idx % 48) * 64; r0 = (idx / 48) * 64;
  } else {
    const int idx = bid - 1792;            // 16 x 16 blocks
    W = w_proj; WT = wprojT; K = 1024; N = 1024;
    c0 = (idx & 15) * 64; r0 = (idx >> 4) * 64;
  }
  const int tr = t >> 4, tc4 = (t & 15) * 4;
#pragma unroll
  for (int i = 0; i < 4; i++) {
    const int r = tr + 16 * i;
    float4 f = *(const float4*)&W[(size_t)(r0 + r) * N + c0 + tc4];
    ushort4 o;
    o.x = f2bf(f.x); o.y = f2bf(f.y); o.z = f2bf(f.z); o.w = f2bf(f.w);
    *(ushort4*)&tile[r][tc4] = o;
  }
  __syncthreads();
  const int oc = t >> 2, or0 = (t & 3) * 16;
  u16 vals[16];
#pragma unroll
  for (int j = 0; j < 16; j++) vals[j] = tile[or0 + j][oc];
  u16* dst = &WT[(size_t)(c0 + oc) * K + r0 + or0];
  *(uint4*)dst = *(const uint4*)&vals[0];
  *(uint4*)(dst + 8) = *(const uint4*)&vals[8];
}

// ---------------- GEMM: C[M,N] = A[M,K](bf16) @ BT[N,K]^T + bias ----------------
// 128x128 tile, BK=32, 4 waves, double-buffered LDS, one barrier per k-step.
// MODE 0: scatter q/k bf16 [B,H,S,D], v bf16 [B,H,D,S] (transposed, vectorized).
// MODE 1: f32 out + bias.
template <int MODE>
__global__ __launch_bounds__(256) void k_gemm(const u16* __restrict__ A,
                                              const u16* __restrict__ BT,
                                              const float* __restrict__ bias,
                                              float* __restrict__ Cout,
                                              u16* __restrict__ q_ws,
                                              u16* __restrict__ k_ws,
                                              u16* __restrict__ v_t,
                                              int N, int K) {
  __shared__ u16 As[2][128 * 32];
  __shared__ u16 Bs[2][128 * 32];
  const int tid = threadIdx.x;
  const int w = tid >> 6, lane = tid & 63;
  const int wr = w >> 1, wc = w & 1;
  const int lrow = lane & 15, lk8 = (lane >> 4) * 8;
  const int brow = blockIdx.y * 128, bcol = blockIdx.x * 128;
  const int srow = lane >> 2;          // 0..15 within chunk
  const int scol = (lane & 3) * 8;     // 0,8,16,24

  const f32x4 zero = {0.f, 0.f, 0.f, 0.f};
  f32x4 acc[4][4];
#pragma unroll
  for (int m = 0; m < 4; m++)
#pragma unroll
    for (int n = 0; n < 4; n++) acc[m][n] = zero;

  auto stage = [&](int kt, int buf) {
#pragma unroll
    for (int i = 0; i < 2; i++) {
      const int c = w * 2 + i;               // chunk 0..7, 1KB each (linear LDS)
      const int row = c * 16 + srow;
      gld_lds16(&A[(size_t)(brow + row) * K + kt + scol], (void*)(&As[buf][c * 512]));
      gld_lds16(&BT[(size_t)(bcol + row) * K + kt + scol], (void*)(&Bs[buf][c * 512]));
    }
  };

  const int NK = K >> 5;
  stage(0, 0);
  __syncthreads();
  for (int it = 0; it < NK; ++it) {
    const int cur = it & 1;
    if (it + 1 < NK) stage((it + 1) << 5, cur ^ 1);
    bf16x8 af[4], bfr[4];
#pragma unroll
    for (int mt = 0; mt < 4; mt++)
      af[mt] = *(const bf16x8*)&As[cur][(wr * 64 + mt * 16 + lrow) * 32 + lk8];
#pragma unroll
    for (int nt = 0; nt < 4; nt++)
      bfr[nt] = *(const bf16x8*)&Bs[cur][(wc * 64 + nt * 16 + lrow) * 32 + lk8];
    __builtin_amdgcn_s_setprio(1);
#pragma unroll
    for (int mt = 0; mt < 4; mt++)
#pragma unroll
      for (int nt = 0; nt < 4; nt++)
        acc[mt][nt] = __builtin_amdgcn_mfma_f32_16x16x32_bf16(af[mt], bfr[nt],
                                                              acc[mt][nt], 0, 0, 0);
    __builtin_amdgcn_s_setprio(0);
    __syncthreads();
  }

  if constexpr (MODE == 0) {
    const int which = bcol >> 10;   // uniform per block (0=q, 1=k, 2=v)
#pragma unroll
    for (int mt = 0; mt < 4; mt++)
#pragma unroll
      for (int nt = 0; nt < 4; nt++) {
        const int col = bcol + wc * 64 + nt * 16 + lrow;
        const int e = col & 1023;
        const int h = e >> 6, d = e & 63;
        const int row0 = brow + wr * 64 + mt * 16 + (lane >> 4) * 4;
        const int b = row0 >> 11, s0 = row0 & 2047;
        const size_t bh = (size_t)(b * NH + h);
        const float bv = bias[col];
        if (which == 2) {
          ushort4 pk;
          pk.x = f2bf(acc[mt][nt][0] + bv);
          pk.y = f2bf(acc[mt][nt][1] + bv);
          pk.z = f2bf(acc[mt][nt][2] + bv);
          pk.w = f2bf(acc[mt][nt][3] + bv);
          *(ushort4*)&v_t[(bh * HD + d) * S_LEN + s0] = pk;
        } else {
          u16* dst = which ? k_ws : q_ws;
#pragma unroll
          for (int r = 0; r < 4; r++)
            dst[(bh * S_LEN + s0 + r) * HD + d] = f2bf(acc[mt][nt][r] + bv);
        }
      }
  } else {
#pragma unroll
    for (int mt = 0; mt < 4; mt++)
#pragma unroll
      for (int nt = 0; nt < 4; nt++)
#pragma unroll
        for (int r = 0; r < 4; r++) {
          const int row = brow + wr * 64 + mt * 16 + (lane >> 4) * 4 + r;
          const int col = bcol + wc * 64 + nt * 16 + lrow;
          Cout[(size_t)row * N + col] = acc[mt][nt][r] + bias[col];
        }
  }
}

// ---------------- causal flash attention ------------------------------------
// grid (16, B*H), 256 threads, pair-balanced {pr, 31-pr}, K/V double-buffered.
// SWAPPED QK^T -> S[kv][q]; P in registers via cvt_pk + permlane routing;
// PV = mfma(V^T, P) -> O[d][q]. R10: raw-domain max + single post-reduce
// scale; exp2 arg via FMA (kills 16 muls/process); packed-f32 sum tree.
__global__ __launch_bounds__(256, 2) void k_attn(const u16* __restrict__ q_ws,
                                                 const u16* __restrict__ k_ws,
                                                 const u16* __restrict__ v_t,
                                                 u16* __restrict__ y) {
  __shared__ u16 Kl[2][64 * 64];     // XOR-swizzled rows (16B blocks), [kv][d]
  __shared__ u16 Vl[2][64 * 64];     // XOR-swizzled rows, [d][kv]
  const int tid = threadIdx.x;
  const int w = tid >> 6, lane = tid & 63;
  const int lrow = lane & 15, lk8 = (lane >> 4) * 8;
  const int g4 = (lane >> 4) * 4;
  const int pr = blockIdx.x;               // 0..15
  const int tileA = pr, tileB = 31 - pr;   // tileA < tileB, work = const 33
  const int bh = blockIdx.y;
  const size_t base = (size_t)bh * S_LEN * HD;
  const float SC = 0.125f * 1.4426950408889634f;  // D^-0.5 * log2(e)

  bf16x8 qfA[2], qfB[2];
#pragma unroll
  for (int ks = 0; ks < 2; ks++) {
    qfA[ks] = *(const bf16x8*)&q_ws[base + (size_t)(tileA * 64 + w * 16 + lrow) * HD + ks * 32 + lk8];
    qfB[ks] = *(const bf16x8*)&q_ws[base + (size_t)(tileB * 64 + w * 16 + lrow) * HD + ks * 32 + lk8];
  }

  const f32x4 zero = {0.f, 0.f, 0.f, 0.f};
  f32x4 oA[4], oB[4];                 // O[d][q]: d = dt*16 + g4 + r, q = lrow
#pragma unroll
  for (int dt = 0; dt < 4; dt++) { oA[dt] = zero; oB[dt] = zero; }
  float mA = -1e30f, lA = 0.f, mB = -1e30f, lB = 0.f;

  auto stage = [&](int jb, int buf) {
#pragma unroll
    for (int i = 0; i < 2; i++) {
      const int c = w * 2 + i;
      const int row = c * 8 + (lane >> 3);
      const int blk = (lane & 7) ^ (row & 7);
      gld_lds16(&k_ws[base + (size_t)(jb * 64 + row) * HD + blk * 8],
                (void*)(&Kl[buf][c * 512]));
      gld_lds16(&v_t[base + (size_t)row * S_LEN + jb * 64 + blk * 8],
                (void*)(&Vl[buf][c * 512]));
    }
  };

  auto process = [&](const bf16x8 (&kf)[2][4], const bf16x8 (&vf)[2][4],
                     const bf16x8 (&qf)[2], f32x4 (&o)[4], float& m_run,
                     float& l_run, bool maskDiag) {
    // S = K Q^T (swapped): sa[nt][r] = S[kv = nt*16+g4+r][q = lrow]
    f32x4 sa[4];
#pragma unroll
    for (int nt = 0; nt < 4; nt++) sa[nt] = zero;
    __builtin_amdgcn_s_setprio(1);
#pragma unroll
    for (int ks = 0; ks < 2; ks++)
#pragma unroll
      for (int nt = 0; nt < 4; nt++)
        sa[nt] = __builtin_amdgcn_mfma_f32_16x16x32_bf16(kf[ks][nt], qf[ks], sa[nt], 0, 0, 0);
    __builtin_amdgcn_s_setprio(0);

    // RAW-domain S with optional mask (uniform branch; 2 of 33 calls)
    float sv[4][4];
    if (maskDiag) {
#pragma unroll
      for (int nt = 0; nt < 4; nt++)
#pragma unroll
        for (int r = 0; r < 4; r++)
          sv[nt][r] = ((nt * 16 + g4 + r) > (w * 16 + lrow)) ? -3.0e38f : sa[nt][r];
    } else {
#pragma unroll
      for (int nt = 0; nt < 4; nt++)
#pragma unroll
        for (int r = 0; r < 4; r++) sv[nt][r] = sa[nt][r];
    }

    // max over raw values; scale ONCE after the reduce (was 16 muls)
    float mx = fmaxf(fmaxf(fmaxf(sv[0][0], sv[0][1]), fmaxf(sv[0][2], sv[0][3])),
                     fmaxf(fmaxf(sv[1][0], sv[1][1]), fmaxf(sv[1][2], sv[1][3])));
    mx = fmaxf(mx,
               fmaxf(fmaxf(fmaxf(sv[2][0], sv[2][1]), fmaxf(sv[2][2], sv[2][3])),
                     fmaxf(fmaxf(sv[3][0], sv[3][1]), fmaxf(sv[3][2], sv[3][3]))));
    mx = red4rows_max(mx);
    const float mxs = mx * SC;
    // defer-max (T13): skip rescale when max growth <= 8 (P bounded by 2^8)
    const bool nogrow = __all(mxs <= m_run + 8.0f);
    float mn = m_run;
    if (!nogrow) {
      mn = fmaxf(m_run, mxs);
      const float alpha = fexp2(m_run - mn);
      l_run *= alpha;
#pragma unroll
      for (int dt = 0; dt < 4; dt++) o[dt] *= alpha;
      m_run = mn;
    }
    const float nmn = -mn;
    // p = exp2(fma(sv, SC, -mn)); keep float2 pairs for sum tree + cvt_pk
    f32x2 p2[4][2];
#pragma unroll
    for (int nt = 0; nt < 4; nt++)
#pragma unroll
      for (int h = 0; h < 2; h++) {
        const float a = fexp2(__builtin_fmaf(sv[nt][2 * h], SC, nmn));
        const float b = fexp2(__builtin_fmaf(sv[nt][2 * h + 1], SC, nmn));
        f32x2 p; p[0] = a; p[1] = b;
        p2[nt][h] = p;
      }
    // packed-f32 sum tree (7 pk_add + 1 add, was 15 adds)
    f32x2 s0 = pk_add(p2[0][0], p2[0][1]);
    f32x2 s1 = pk_add(p2[1][0], p2[1][1]);
    f32x2 s2 = pk_add(p2[2][0], p2[2][1]);
    f32x2 s3 = pk_add(p2[3][0], p2[3][1]);
    s0 = pk_add(s0, s1);
    s2 = pk_add(s2, s3);
    s0 = pk_add(s0, s2);
    float sum = s0[0] + s0[1];
    sum = red4rows_sum(sum);
    l_run += sum;

    // P -> PV B-operand entirely in registers (builtin permlane swaps).
    unsigned pk[4][2];
#pragma unroll
    for (int nt = 0; nt < 4; nt++) {
      pk[nt][0] = cvt_pk_bf16(p2[nt][0][0], p2[nt][0][1]);
      pk[nt][1] = cvt_pk_bf16(p2[nt][1][0], p2[nt][1][1]);
    }
    union { unsigned u[4]; bf16x8 v; } c0, c1;
    {
      auto r0 = __builtin_amdgcn_permlane32_swap(pk[0][0], pk[1][0], false, false);
      auto s0p = __builtin_amdgcn_permlane16_swap(r0[0], r0[1], false, false);
      auto r1 = __builtin_amdgcn_permlane32_swap(pk[0][1], pk[1][1], false, false);
      auto s1p = __builtin_amdgcn_permlane16_swap(r1[0], r1[1], false, false);
      c0.u[0] = s0p[0]; c0.u[1] = s1p[0]; c0.u[2] = s0p[1]; c0.u[3] = s1p[1];
      auto r2 = __builtin_amdgcn_permlane32_swap(pk[2][0], pk[3][0], false, false);
      auto s2p = __builtin_amdgcn_permlane16_swap(r2[0], r2[1], false, false);
      auto r3 = __builtin_amdgcn_permlane32_swap(pk[2][1], pk[3][1], false, false);
      auto s3p = __builtin_amdgcn_permlane16_swap(r3[0], r3[1], false, false);
      c1.u[0] = s2p[0]; c1.u[1] = s3p[0]; c1.u[2] = s2p[1]; c1.u[3] = s3p[1];
    }
    bf16x8 pfrag[2] = {c0.v, c1.v};

    // O += V^T P : o[dt] rows d = dt*16+g4+r, col q = lrow
    __builtin_amdgcn_s_setprio(1);
#pragma unroll
    for (int ks = 0; ks < 2; ks++)
#pragma unroll
      for (int dt = 0; dt < 4; dt++)
        o[dt] = __builtin_amdgcn_mfma_f32_16x16x32_bf16(vf[ks][dt], pfrag[ks], o[dt], 0, 0, 0);
    __builtin_amdgcn_s_setprio(0);
  };

  stage(0, 0);
  __syncthreads();
  for (int jb = 0; jb <= tileB; jb++) {
    const int cur = jb & 1;
    if (jb < tileB) stage(jb + 1, cur ^ 1);
    // Hoist K AND V fragments once per tile — shared by both process calls.
    bf16x8 kf[2][4], vf[2][4];
#pragma unroll
    for (int ks = 0; ks < 2; ks++)
#pragma unroll
      for (int nt = 0; nt < 4; nt++) {
        const int kvr = nt * 16 + lrow;
        const int blk = (ks * 4 + (lane >> 4)) ^ (kvr & 7);
        kf[ks][nt] = *(const bf16x8*)&Kl[cur][kvr * 64 + blk * 8];
        vf[ks][nt] = *(const bf16x8*)&Vl[cur][kvr * 64 + blk * 8];
      }
    process(kf, vf, qfB, oB, mB, lB, jb == tileB);
    if (jb <= tileA) process(kf, vf, qfA, oA, mA, lA, jb == tileA);
    __syncthreads();
  }

  const int b = bh >> 4, h = bh & 15;
  const float invA = 1.0f / lA;
  const float invB = 1.0f / lB;
  const int qgA = tileA * 64 + w * 16 + lrow;
  const int qgB = tileB * 64 + w * 16 + lrow;
#pragma unroll
  for (int dt = 0; dt < 4; dt++) {
    uint2 pa, pb;
    pa.x = cvt_pk_bf16(oA[dt][0] * invA, oA[dt][1] * invA);
    pa.y = cvt_pk_bf16(oA[dt][2] * invA, oA[dt][3] * invA);
    pb.x = cvt_pk_bf16(oB[dt][0] * invB, oB[dt][1] * invB);
    pb.y = cvt_pk_bf16(oB[dt][2] * invB, oB[dt][3] * invB);
    *(uint2*)&y[(size_t)(b * S_LEN + qgA) * EMB + h * HD + dt * 16 + g4] = pa;
    *(uint2*)&y[(size_t)(b * S_LEN + qgB) * EMB + h * HD + dt * 16 + g4] = pb;
  }
}

extern "C" void kernel_launch(void* const* d_in, const int* in_sizes, int n_in,
                              void* d_out, int out_size, void* d_ws, size_t ws_size,
                              hipStream_t stream) {
  const float* x      = (const float*)d_in[0];
  const float* w_qkv  = (const float*)d_in[1];
  const float* b_qkv  = (const float*)d_in[2];
  const float* w_proj = (const float*)d_in[3];
  const float* b_proj = (const float*)d_in[4];
  float* out = (float*)d_out;

  char* ws = (char*)d_ws;
  u16* wqkvT  = (u16*)(ws);                  // 3072x1024 bf16 (6 MB)
  u16* wprojT = (u16*)(ws + 6291456);        // 1024x1024 bf16 (2 MB)
  u16* xb     = (u16*)(ws + 8388608);        // 8192x1024 bf16 (16 MB), reused as y_att
  u16* q_ws   = (u16*)(ws + 25165824);       // [B,H,S,D] bf16 (16 MB)
  u16* k_ws   = (u16*)(ws + 41943040);       // [B,H,S,D]
  u16* v_t    = (u16*)(ws + 58720256);       // [B,H,D,S] (transposed!)  end: 72 MB
  u16* y_att  = xb;                          // x dead after GEMM1

  k_prep<<<dim3(2048), dim3(256), 0, stream>>>(x, xb, w_qkv, wqkvT, w_proj, wprojT);
  k_gemm<0><<<dim3(24, 64), dim3(256), 0, stream>>>(xb, wqkvT, b_qkv, nullptr,
                                                    q_ws, k_ws, v_t, 3072, 1024);
  k_attn<<<dim3(16, 64), dim3(256), 0, stream>>>(q_ws, k_ws, v_t, y_att);
  k_gemm<1><<<dim3(8, 64), dim3(256), 0, stream>>>(y_att, wprojT, b_proj, out,
                                                   nullptr, nullptr, nullptr, 1024, 1024);
}